// Round 17
// baseline (247.772 us; speedup 1.0000x reference)
//
#include <hip/hip_runtime.h>
#include <math.h>

#define N_NODES 50000
#define N_EDGES 800000
#define ET (N_EDGES + N_NODES)
#define IN_F 128
#define TDIM 64
#define HEADS 4
#define C0 64
#define C1 16
#define HC0 256
#define HC1 64
#define KF 512 /* fused K = 4*IN_F */
#define SLOPE 0.2f
#define TAB 4096
#define BSHIFT 7
#define NBUCKET 391 /* ceil(50000/128) */
#define BCAP 4096   /* staging capacity per bucket (E~2048, sigma~45) */
#define CHUNK 512   /* small chunks -> 1563 blocks -> latency hiding */

using short8 = __attribute__((ext_vector_type(8))) short;
using f32x4 = __attribute__((ext_vector_type(4))) float;

__device__ __forceinline__ float bf2f(unsigned u16) { return __uint_as_float(u16 << 16); }
__device__ __forceinline__ unsigned short f2bf(float f) {
    unsigned u = __float_as_uint(f);
    return (unsigned short)((u + 0x7fffu + ((u >> 16) & 1u)) >> 16);
}
__device__ __forceinline__ unsigned pk2(float lo, float hi) {
    return (unsigned)f2bf(lo) | ((unsigned)f2bf(hi) << 16);
}
__device__ __forceinline__ float lrelu(float a) { return a >= 0.f ? a : SLOPE * a; }

// ---------------------------------------------------------------------------
// ALL parameter-only precompute in ONE launch (275 blocks x 256):
//  b == 0        : l0/l1[h] (self-loop logits)
//  b in [1,129)  : as0/ad0[h][k] layer-0 score tables
//  b in [129,257): W01t (bf16 fused W0*W1, transposed)
//  b == 257      : b01 (fused bias)
//  b in [258,275): time-encode tables tab0/tab1 (self-computed v contraction)
__global__ __launch_bounds__(256) void k_param(
    const float* __restrict__ le0, const float* __restrict__ at0, const float* __restrict__ le1,
    const float* __restrict__ at1, const float* __restrict__ W0, const float* __restrict__ asr,
    const float* __restrict__ ads, const float* __restrict__ W1, const float* __restrict__ bias0,
    const float* __restrict__ tw, const float* __restrict__ tb, float* __restrict__ l0,
    float* __restrict__ l1, float* __restrict__ as0, float* __restrict__ ad0,
    unsigned short* __restrict__ W01t, float* __restrict__ b01, float* __restrict__ tab0,
    float* __restrict__ tab1) {
    int b = blockIdx.x, tid = threadIdx.x;
    int h = tid >> 6, c = tid & 63;
    if (b == 0) {
        float s0 = 0.f;
        for (int td = 0; td < TDIM; ++td) s0 += le0[td * HC0 + h * C0 + c];
        s0 *= at0[h * C0 + c];
        for (int m = 1; m < 64; m <<= 1) s0 += __shfl_xor(s0, m);
        if (c == 0) l0[h] = s0;
        float s1 = 0.f;
        if (c < C1) {
            for (int td = 0; td < TDIM; ++td) s1 += le1[td * HC1 + h * C1 + c];
            s1 *= at1[h * C1 + c];
        }
        for (int m = 1; m < 16; m <<= 1) s1 += __shfl_xor(s1, m);
        if (c == 0) l1[h] = s1;
    } else if (b < 129) {
        int k = b - 1;
        float wv = W0[k * HC0 + h * C0 + c];
        float ps = wv * asr[h * C0 + c];
        float pd = wv * ads[h * C0 + c];
        for (int m = 1; m < 64; m <<= 1) {
            ps += __shfl_xor(ps, m);
            pd += __shfl_xor(pd, m);
        }
        if (c == 0) {
            as0[h * IN_F + k] = ps;
            ad0[h * IN_F + k] = pd;
        }
    } else if (b < 257) {
        int hk = (b - 129) * 4 + (tid >> 6);
        int c1 = tid & 63;
        int hh = hk >> 7, k = hk & 127;
        float acc = 0.f;
        for (int c0 = 0; c0 < C0; ++c0)
            acc += W0[k * HC0 + hh * C0 + c0] * W1[(size_t)(hh * C0 + c0) * HC1 + c1];
        W01t[(size_t)c1 * KF + hk] = f2bf(acc);
    } else if (b == 257) {
        if (tid < 64) {
            float acc = 0.f;
            for (int k = 0; k < HC0; ++k) acc += bias0[k] * W1[(size_t)k * HC1 + tid];
            b01[tid] = acc;
        }
    } else {
        // time-encode table blocks: self-compute v contraction in LDS
        __shared__ float sv0[TDIM * 4], sv1[TDIM * 4], sw[TDIM], sb[TDIM];
        int td = tid >> 2, hh = tid & 3;
        float v0l = 0.f;
        for (int c0 = 0; c0 < C0; ++c0) v0l += le0[td * HC0 + hh * C0 + c0] * at0[hh * C0 + c0];
        sv0[td * 4 + hh] = v0l;
        float v1l = 0.f;
        for (int c0 = 0; c0 < C1; ++c0) v1l += le1[td * HC1 + hh * C1 + c0] * at1[hh * C1 + c0];
        sv1[td * 4 + hh] = v1l;
        if (tid < TDIM) {
            sw[tid] = tw[tid];
            sb[tid] = tb[tid];
        }
        __syncthreads();
        int i = (b - 258) * 256 + tid;
        if (i > TAB) return;
        float time = (float)i / (float)TAB;
        float a00 = 0, a01 = 0, a02 = 0, a03 = 0, a10 = 0, a11 = 0, a12 = 0, a13 = 0;
#pragma unroll 8
        for (int d = 0; d < TDIM; ++d) {
            float f = fabsf(__cosf(time * sw[d] + sb[d]));
            a00 += f * sv0[d * 4 + 0];
            a01 += f * sv0[d * 4 + 1];
            a02 += f * sv0[d * 4 + 2];
            a03 += f * sv0[d * 4 + 3];
            a10 += f * sv1[d * 4 + 0];
            a11 += f * sv1[d * 4 + 1];
            a12 += f * sv1[d * 4 + 2];
            a13 += f * sv1[d * 4 + 3];
        }
        ((float4*)tab0)[i] = make_float4(a00, a01, a02, a03);
        ((float4*)tab1)[i] = make_float4(a10, a11, a12, a13);
    }
}

// ---------------------------------------------------------------------------
// Fused x->bf16 + layer-0 scores + deg/bcnt zeroing. One wave per node.
__global__ __launch_bounds__(256) void k_xbs(const float* __restrict__ x,
                                             const float* __restrict__ as0,
                                             const float* __restrict__ ad0,
                                             unsigned short* __restrict__ xb,
                                             float* __restrict__ ssrc, float* __restrict__ sdst,
                                             int* __restrict__ deg, int* __restrict__ bcnt) {
    if (blockIdx.x < 196) {
        int i = blockIdx.x * 256 + threadIdx.x;
        if (i < N_NODES) deg[i] = 0;
    }
    if (blockIdx.x >= 196 && blockIdx.x < 198) {
        int i = (blockIdx.x - 196) * 256 + threadIdx.x;
        if (i < NBUCKET) bcnt[i] = 0;
    }
    int w = threadIdx.x >> 6, l = threadIdx.x & 63;
    int n = blockIdx.x * 4 + w;
    if (n >= N_NODES) return;
    float2 xv = *(const float2*)(x + (size_t)n * IN_F + l * 2);
    *(unsigned*)(xb + (size_t)n * IN_F + l * 2) = pk2(xv.x, xv.y);
    float ps[4], pd[4];
#pragma unroll
    for (int h = 0; h < 4; ++h) {
        float2 a = *(const float2*)(as0 + h * IN_F + l * 2);
        float2 d = *(const float2*)(ad0 + h * IN_F + l * 2);
        ps[h] = xv.x * a.x + xv.y * a.y;
        pd[h] = xv.x * d.x + xv.y * d.y;
    }
#pragma unroll
    for (int m = 1; m < 64; m <<= 1) {
#pragma unroll
        for (int h = 0; h < 4; ++h) {
            ps[h] += __shfl_xor(ps[h], m);
            pd[h] += __shfl_xor(pd[h], m);
        }
    }
    if (l == 0) {
#pragma unroll
        for (int h = 0; h < 4; ++h) {
            ssrc[n * 4 + h] = ps[h];
            sdst[n * 4 + h] = pd[h];
        }
    }
}

// ---------------------------------------------------------------------------
// Phase A: bucket edges by dst>>7 into FIXED per-bucket staging windows
// (b*BCAP) AND count per-node degrees. CHUNK=512 -> 1563 blocks for TLP.
// Staging packed int2: .x = (src<<7) | (dst & 127), .y = ts bits
__global__ __launch_bounds__(256) void k_bucketA(const int* __restrict__ ei,
                                                 const float* __restrict__ ts,
                                                 int* __restrict__ deg, int* __restrict__ bcnt,
                                                 int2* __restrict__ staging) {
    __shared__ int cnt[NBUCKET], base[NBUCKET];
    int tid = threadIdx.x;
    int e0 = blockIdx.x * CHUNK;
    for (int i = tid; i < NBUCKET; i += 256) cnt[i] = 0;
    __syncthreads();
    int key[2], b[2], tv[2];
#pragma unroll
    for (int i = 0; i < 2; ++i) {
        int tt = e0 + i * 256 + tid;
        if (tt < N_EDGES) {
            int s = ei[tt];
            int d = ei[N_EDGES + tt];
            key[i] = (s << BSHIFT) | (d & ((1 << BSHIFT) - 1));
            b[i] = d >> BSHIFT;
            tv[i] = __float_as_int(ts[tt]);
            atomicAdd(&cnt[b[i]], 1);
            atomicAdd(&deg[d], 1);  // fused per-node degree count
        } else {
            b[i] = -1;
        }
    }
    __syncthreads();
    for (int i = tid; i < NBUCKET; i += 256) {
        int c = cnt[i];
        base[i] = c ? atomicAdd(&bcnt[i], c) : 0;
        cnt[i] = 0;  // reuse as running cursor
    }
    __syncthreads();
#pragma unroll
    for (int i = 0; i < 2; ++i) {
        if (b[i] >= 0) {
            int off = atomicAdd(&cnt[b[i]], 1);
            staging[(size_t)b[i] * BCAP + base[b[i]] + off] = make_int2(key[i], tv[i]);
        }
    }
}

// ---------------------------------------------------------------------------
// Hierarchical scan (multi-block). deg+1 = reserved self-loop slot per row.
__global__ void k_scan_block(const int* __restrict__ deg, int* __restrict__ rowptr,
                             int* __restrict__ blocksum, int n) {
    __shared__ int buf[256];
    int tid = threadIdx.x, i = blockIdx.x * 256 + tid;
    int v = (i < n) ? (deg[i] + 1) : 0;
    buf[tid] = v;
    __syncthreads();
    for (int off = 1; off < 256; off <<= 1) {
        int t = (tid >= off) ? buf[tid - off] : 0;
        __syncthreads();
        buf[tid] += t;
        __syncthreads();
    }
    if (i < n) rowptr[i + 1] = buf[tid];
    if (tid == 255) blocksum[blockIdx.x] = buf[255];
}

__global__ void k_scan_top(const int* __restrict__ blocksum, int* __restrict__ blockoff, int nb) {
    __shared__ int buf[256];
    int tid = threadIdx.x;
    int v = (tid < nb) ? blocksum[tid] : 0;
    buf[tid] = v;
    __syncthreads();
    for (int off = 1; off < 256; off <<= 1) {
        int t = (tid >= off) ? buf[tid - off] : 0;
        __syncthreads();
        buf[tid] += t;
        __syncthreads();
    }
    if (tid < nb) blockoff[tid] = buf[tid] - v;  // exclusive
}

// Finalize: rowptr += blockoff; cursor, edst spans (incl. self-loop slot),
// self-loop esrc/tsp/ew0p.
__global__ void k_finalize(int* __restrict__ rowptr, const int* __restrict__ blockoff,
                           const int* __restrict__ deg, int* __restrict__ cursor,
                           int* __restrict__ edst, int* __restrict__ esrc,
                           float* __restrict__ tsp, const float* __restrict__ ssrc0,
                           const float* __restrict__ sdst0, const float* __restrict__ l0,
                           float* __restrict__ ew0p) {
    int i = blockIdx.x * 256 + threadIdx.x;
    if (i >= N_NODES) return;
    int v = rowptr[i + 1] + blockoff[blockIdx.x];
    rowptr[i + 1] = v;
    int start = v - deg[i] - 1;
    cursor[i] = start;
    if (i == 0) rowptr[0] = 0;
    for (int p = start; p < v; ++p) edst[p] = i;  // includes self-loop slot
    esrc[v - 1] = i;                              // self-loop src
    tsp[v - 1] = -1.f;                            // self-loop sentinel
    float4 lv = ((const float4*)l0)[0];
    float4 sv = ((const float4*)ssrc0)[i];
    float4 dv = ((const float4*)sdst0)[i];
    float4 w;
    w.x = __expf(lrelu(sv.x + dv.x + lv.x));
    w.y = __expf(lrelu(sv.y + dv.y + lv.y));
    w.z = __expf(lrelu(sv.z + dv.z + lv.z));
    w.w = __expf(lrelu(sv.w + dv.w + lv.w));
    ((float4*)ew0p)[v - 1] = w;
}

// ---------------------------------------------------------------------------
// Phase B: one block per bucket; scatter from fixed staging window into final
// CSR slots (L2-hot) AND compute layer-0 edge softmax weights (edge-parallel).
__global__ __launch_bounds__(256) void k_bucketB(
    const int* __restrict__ bcnt, const int2* __restrict__ staging, int* __restrict__ cursor,
    int* __restrict__ esrc, float* __restrict__ tsp, const float* __restrict__ ssrc0,
    const float* __restrict__ sdst0, const float* __restrict__ tab0, float* __restrict__ ew0p) {
    int b = blockIdx.x;
    int hi = bcnt[b];
    const int2* win = staging + (size_t)b * BCAP;
    for (int p = threadIdx.x; p < hi; p += 256) {
        int2 kt = win[p];
        int s = ((unsigned)kt.x) >> BSHIFT;
        int d = (b << BSHIFT) | (kt.x & ((1 << BSHIFT) - 1));
        int q = atomicAdd(&cursor[d], 1);
        esrc[q] = s;
        float tv = __int_as_float(kt.y);
        tsp[q] = tv;
        float f = tv * (float)TAB;
        int i = (int)f;
        i = i > TAB - 1 ? TAB - 1 : i;
        float fr = f - (float)i;
        float4 t0 = ((const float4*)tab0)[i];
        float4 t1 = ((const float4*)tab0)[i + 1];
        float4 sv = ((const float4*)ssrc0)[s];
        float4 dv = ((const float4*)sdst0)[d];
        float4 w;
        w.x = __expf(lrelu(sv.x + dv.x + t0.x + fr * (t1.x - t0.x)));
        w.y = __expf(lrelu(sv.y + dv.y + t0.y + fr * (t1.y - t0.y)));
        w.z = __expf(lrelu(sv.z + dv.z + t0.z + fr * (t1.z - t0.z)));
        w.w = __expf(lrelu(sv.w + dv.w + t0.w + fr * (t1.w - t0.w)));
        ((float4*)ew0p)[q] = w;
    }
}

// ---------------------------------------------------------------------------
// Layer-1 edge weights (edge-parallel, streaming, table lerp).
__global__ void k_ew1(const int* __restrict__ esrc, const int* __restrict__ edst,
                      const float* __restrict__ tsp, const float* __restrict__ tab1,
                      const float* __restrict__ l1, const float* __restrict__ ssrc,
                      const float* __restrict__ sdst, float* __restrict__ ew1p) {
    int p = blockIdx.x * blockDim.x + threadIdx.x;
    if (p >= ET) return;
    float tv = tsp[p];
    float4 av;
    if (tv < 0.f) {
        av = ((const float4*)l1)[0];
    } else {
        float f = tv * (float)TAB;
        int i = (int)f;
        i = i > TAB - 1 ? TAB - 1 : i;
        float fr = f - (float)i;
        float4 t0 = ((const float4*)tab1)[i];
        float4 t1 = ((const float4*)tab1)[i + 1];
        av.x = t0.x + fr * (t1.x - t0.x);
        av.y = t0.y + fr * (t1.y - t0.y);
        av.z = t0.z + fr * (t1.z - t0.z);
        av.w = t0.w + fr * (t1.w - t0.w);
    }
    int s = esrc[p], d = edst[p];
    float4 sv = ((const float4*)ssrc)[s];
    float4 dv = ((const float4*)sdst)[d];
    float4 w;
    w.x = __expf(lrelu(sv.x + dv.x + av.x));
    w.y = __expf(lrelu(sv.y + dv.y + av.y));
    w.z = __expf(lrelu(sv.z + dv.z + av.z));
    w.w = __expf(lrelu(sv.w + dv.w + av.w));
    ((float4*)ew1p)[p] = w;
}

// ---------------------------------------------------------------------------
// Layer-0 aggregation of x, precomputed weights, software-pipelined gather.
// 4 nodes per wave (16-lane groups), lane owns 8 channels (all 4 heads).
// Regular stores (aggx is re-read by GEMM; keep it L2-resident).
__global__ __launch_bounds__(256) void k_aggx(const unsigned short* __restrict__ xb,
                                              const int* __restrict__ esrc,
                                              const float* __restrict__ ew0p,
                                              const int* __restrict__ rowptr,
                                              unsigned short* __restrict__ aggx) {
    int grp = threadIdx.x >> 4, lo = threadIdx.x & 15;
    int n = blockIdx.x * 16 + grp;
    if (n >= N_NODES) return;
    int p0 = rowptr[n], p1 = rowptr[n + 1];  // p1 > p0 always (self-loop)
    float acc[4][8];
#pragma unroll
    for (int h = 0; h < 4; ++h)
#pragma unroll
        for (int j = 0; j < 8; ++j) acc[h][j] = 0.f;
    float ss0 = 0, ss1 = 0, ss2 = 0, ss3 = 0;
    float4 e_cur = ((const float4*)ew0p)[p0];
    uint4 x_cur = *(const uint4*)(xb + (size_t)esrc[p0] * IN_F + lo * 8);
    int s_nxt = (p0 + 1 < p1) ? esrc[p0 + 1] : 0;
    for (int p = p0; p < p1; ++p) {
        float4 e = e_cur;
        uint4 xv = x_cur;
        if (p + 1 < p1) {
            e_cur = ((const float4*)ew0p)[p + 1];
            x_cur = *(const uint4*)(xb + (size_t)s_nxt * IN_F + lo * 8);
            if (p + 2 < p1) s_nxt = esrc[p + 2];
        }
        float f[8];
        f[0] = bf2f(xv.x & 0xffff);
        f[1] = bf2f(xv.x >> 16);
        f[2] = bf2f(xv.y & 0xffff);
        f[3] = bf2f(xv.y >> 16);
        f[4] = bf2f(xv.z & 0xffff);
        f[5] = bf2f(xv.z >> 16);
        f[6] = bf2f(xv.w & 0xffff);
        f[7] = bf2f(xv.w >> 16);
#pragma unroll
        for (int j = 0; j < 8; ++j) {
            acc[0][j] += e.x * f[j];
            acc[1][j] += e.y * f[j];
            acc[2][j] += e.z * f[j];
            acc[3][j] += e.w * f[j];
        }
        ss0 += e.x;
        ss1 += e.y;
        ss2 += e.z;
        ss3 += e.w;
    }
    float inv[4] = {1.f / (ss0 + 1e-16f), 1.f / (ss1 + 1e-16f), 1.f / (ss2 + 1e-16f),
                    1.f / (ss3 + 1e-16f)};
    size_t base = (size_t)n * KF + lo * 8;
#pragma unroll
    for (int h = 0; h < 4; ++h) {
        uint4 r;
        r.x = pk2(acc[h][0] * inv[h], acc[h][1] * inv[h]);
        r.y = pk2(acc[h][2] * inv[h], acc[h][3] * inv[h]);
        r.z = pk2(acc[h][4] * inv[h], acc[h][5] * inv[h]);
        r.w = pk2(acc[h][6] * inv[h], acc[h][7] * inv[h]);
        *(uint4*)(aggx + base + h * IN_F) = r;
    }
}

// ---------------------------------------------------------------------------
// h1 = aggx @ W01t^T + b01 ; writes h1b (bf16) + fused layer-1 scores
// (epilogue lives here: compute-bound kernel, registers are cheap).
__global__ __launch_bounds__(256) void k_gemm1s(
    const unsigned short* __restrict__ A, const unsigned short* __restrict__ Bt,
    const float* __restrict__ b01, const float* __restrict__ a_src,
    const float* __restrict__ a_dst, unsigned short* __restrict__ h1b, float* __restrict__ ssrc,
    float* __restrict__ sdst) {
    __shared__ unsigned short As[128 * 40];
    __shared__ unsigned short Bs[64 * 40];
    int tid = threadIdx.x, w = tid >> 6, l = tid & 63, lo = l & 15, hi = l >> 4;
    int m0 = blockIdx.x * 128;
    f32x4 acc[2][4];
#pragma unroll
    for (int i = 0; i < 2; ++i)
#pragma unroll
        for (int j = 0; j < 4; ++j) acc[i][j] = (f32x4){0.f, 0.f, 0.f, 0.f};
    int arow4 = tid >> 2, aseg = tid & 3;
    for (int k0 = 0; k0 < KF; k0 += 32) {
#pragma unroll
        for (int hf = 0; hf < 2; ++hf) {
            int arow = hf * 64 + arow4;
            uint4 va = {0, 0, 0, 0};
            if (m0 + arow < N_NODES)
                va = *(const uint4*)(A + (size_t)(m0 + arow) * KF + k0 + aseg * 8);
            *(uint4*)&As[arow * 40 + aseg * 8] = va;
        }
        uint4 vb = *(const uint4*)(Bt + (size_t)arow4 * KF + k0 + aseg * 8);
        *(uint4*)&Bs[arow4 * 40 + aseg * 8] = vb;
        __syncthreads();
        short8 af[2], bf[4];
#pragma unroll
        for (int fa = 0; fa < 2; ++fa)
            af[fa] = *(const short8*)&As[(w * 32 + fa * 16 + lo) * 40 + hi * 8];
#pragma unroll
        for (int nf = 0; nf < 4; ++nf) bf[nf] = *(const short8*)&Bs[(nf * 16 + lo) * 40 + hi * 8];
#pragma unroll
        for (int fa = 0; fa < 2; ++fa)
#pragma unroll
            for (int nf = 0; nf < 4; ++nf)
                acc[fa][nf] =
                    __builtin_amdgcn_mfma_f32_16x16x32_bf16(af[fa], bf[nf], acc[fa][nf], 0, 0, 0);
        __syncthreads();
    }
    float asv[4], adv[4], bv[4];
#pragma unroll
    for (int nf = 0; nf < 4; ++nf) {
        asv[nf] = a_src[nf * 16 + lo];
        adv[nf] = a_dst[nf * 16 + lo];
        bv[nf] = b01[nf * 16 + lo];
    }
#pragma unroll
    for (int fa = 0; fa < 2; ++fa)
#pragma unroll
        for (int r = 0; r < 4; ++r) {
            int row = m0 + w * 32 + fa * 16 + hi * 4 + r;
#pragma unroll
            for (int nf = 0; nf < 4; ++nf) {
                float v = acc[fa][nf][r] + bv[nf];
                if (row < N_NODES) h1b[(size_t)row * HC1 + nf * 16 + lo] = f2bf(v);
                float ps = v * asv[nf], pd = v * adv[nf];
                for (int m = 1; m < 16; m <<= 1) {
                    ps += __shfl_xor(ps, m);
                    pd += __shfl_xor(pd, m);
                }
                if (lo == 0 && row < N_NODES) {
                    ssrc[row * 4 + nf] = ps;
                    sdst[row * 4 + nf] = pd;
                }
            }
        }
}

// ---------------------------------------------------------------------------
// Layer-1 aggregation: 8-lane groups (8 gather chains/wave), lane owns 8
// channels (one uint4 16B load), head = lo>>1. 2-deep esrc prefetch.
// Final output stored non-temporal (never re-read).
__global__ __launch_bounds__(256) void k_agg1(
    const unsigned short* __restrict__ h1b, const int* __restrict__ esrc,
    const float* __restrict__ ew1p, const int* __restrict__ rowptr,
    const float* __restrict__ bias, float* __restrict__ out) {
    int grp = threadIdx.x >> 3, lo = threadIdx.x & 7;
    int n = blockIdx.x * 32 + grp;
    if (n >= N_NODES) return;
    int head = lo >> 1;
    int p0 = rowptr[n], p1 = rowptr[n + 1];
    float a0 = 0, a1 = 0, a2 = 0, a3 = 0, a4 = 0, a5 = 0, a6 = 0, a7 = 0, ss = 0;
    float e_cur = ew1p[p0 * 4 + head];
    uint4 h_cur = *(const uint4*)(h1b + (size_t)esrc[p0] * HC1 + lo * 8);
    int s_nxt = (p0 + 1 < p1) ? esrc[p0 + 1] : 0;
    for (int p = p0; p < p1; ++p) {
        float e = e_cur;
        uint4 hv = h_cur;
        if (p + 1 < p1) {
            e_cur = ew1p[(p + 1) * 4 + head];
            h_cur = *(const uint4*)(h1b + (size_t)s_nxt * HC1 + lo * 8);
            if (p + 2 < p1) s_nxt = esrc[p + 2];
        }
        a0 += e * bf2f(hv.x & 0xffff);
        a1 += e * bf2f(hv.x >> 16);
        a2 += e * bf2f(hv.y & 0xffff);
        a3 += e * bf2f(hv.y >> 16);
        a4 += e * bf2f(hv.z & 0xffff);
        a5 += e * bf2f(hv.z >> 16);
        a6 += e * bf2f(hv.w & 0xffff);
        a7 += e * bf2f(hv.w >> 16);
        ss += e;
    }
    float inv = 1.f / (ss + 1e-16f);
    float4 b0 = *(const float4*)(bias + lo * 8);
    float4 b1 = *(const float4*)(bias + lo * 8 + 4);
    size_t o = (size_t)n * HC1 + lo * 8;
    float4 r0 = make_float4(a0 * inv + b0.x, a1 * inv + b0.y, a2 * inv + b0.z, a3 * inv + b0.w);
    float4 r1 = make_float4(a4 * inv + b1.x, a5 * inv + b1.y, a6 * inv + b1.z, a7 * inv + b1.w);
    float* po = out + o;
    __builtin_nontemporal_store(r0.x, po + 0);
    __builtin_nontemporal_store(r0.y, po + 1);
    __builtin_nontemporal_store(r0.z, po + 2);
    __builtin_nontemporal_store(r0.w, po + 3);
    __builtin_nontemporal_store(r1.x, po + 4);
    __builtin_nontemporal_store(r1.y, po + 5);
    __builtin_nontemporal_store(r1.z, po + 6);
    __builtin_nontemporal_store(r1.w, po + 7);
}

// ---------------------------------------------------------------------------
extern "C" void kernel_launch(void* const* d_in, const int* in_sizes, int n_in, void* d_out,
                              int out_size, void* d_ws, size_t ws_size, hipStream_t stream) {
    const float* x = (const float*)d_in[0];
    const int* ei = (const int*)d_in[1];
    const float* ts = (const float*)d_in[2];
    const float* time_w = (const float*)d_in[3];
    const float* time_b = (const float*)d_in[4];
    const float* W0 = (const float*)d_in[5];
    const float* att_src0 = (const float*)d_in[6];
    const float* att_dst0 = (const float*)d_in[7];
    const float* lin_edge0 = (const float*)d_in[8];
    const float* att_edge0 = (const float*)d_in[9];
    const float* bias0 = (const float*)d_in[10];
    const float* W1 = (const float*)d_in[11];
    const float* att_src1 = (const float*)d_in[12];
    const float* att_dst1 = (const float*)d_in[13];
    const float* lin_edge1 = (const float*)d_in[14];
    const float* att_edge1 = (const float*)d_in[15];
    const float* bias1 = (const float*)d_in[16];
    float* out = (float*)d_out;

    char* ws = (char*)d_ws;
    size_t off = 0;
    auto alloc = [&](size_t bytes) -> void* {
        void* p = ws + off;
        off = (off + bytes + 255) & ~(size_t)255;
        return p;
    };
    unsigned short* xb = (unsigned short*)alloc((size_t)N_NODES * IN_F * 2);
    unsigned short* aggx = (unsigned short*)alloc((size_t)N_NODES * KF * 2);
    unsigned short* h1b = (unsigned short*)alloc((size_t)N_NODES * HC1 * 2);
    unsigned short* W01t = (unsigned short*)alloc((size_t)HC1 * KF * 2);
    float* b01 = (float*)alloc(HC1 * 4);
    float* as0 = (float*)alloc(4 * IN_F * 4);
    float* ad0 = (float*)alloc(4 * IN_F * 4);
    float* tab0 = (float*)alloc((size_t)(TAB + 1) * 4 * 4);
    float* tab1 = (float*)alloc((size_t)(TAB + 1) * 4 * 4);
    float* ew0p = (float*)alloc((size_t)ET * 4 * 4);
    float* ew1p = (float*)alloc((size_t)ET * 4 * 4);
    float* ssrc0 = (float*)alloc((size_t)N_NODES * 4 * 4);
    float* sdst0 = (float*)alloc((size_t)N_NODES * 4 * 4);
    float* ssrc1 = (float*)alloc((size_t)N_NODES * 4 * 4);
    float* sdst1 = (float*)alloc((size_t)N_NODES * 4 * 4);
    float* l0 = (float*)alloc(16);
    float* l1 = (float*)alloc(16);
    float* tsp = (float*)alloc((size_t)ET * 4);
    int* deg = (int*)alloc((size_t)N_NODES * 4);
    int* rowptr = (int*)alloc((size_t)(N_NODES + 1) * 4);
    int* cursor = (int*)alloc((size_t)(N_NODES + 1) * 4);
    int* blocksum = (int*)alloc(256 * 4);
    int* blockoff = (int*)alloc(256 * 4);
    int* bcnt = (int*)alloc(NBUCKET * 4);
    int2* staging = (int2*)alloc((size_t)NBUCKET * BCAP * 8);
    int* esrc = (int*)alloc((size_t)ET * 4);
    int* edst = (int*)alloc((size_t)ET * 4);
    (void)ws_size;
    (void)in_sizes;
    (void)n_in;
    (void)out_size;

    int nb = (N_NODES + 255) / 256;            // 196
    int ebks = (ET + 255) / 256;               // 3321
    int cbks = (N_EDGES + CHUNK - 1) / CHUNK;  // 1563
    int gx = (N_NODES + 127) / 128;            // 391
    int nblk16 = (N_NODES + 15) / 16;          // 3125
    int nblk32 = (N_NODES + 31) / 32;          // 1563
    int nblk4 = (N_NODES + 3) / 4;             // 12500

    // Parameter-only precompute (single launch, incl. time-encode tables)
    k_param<<<275, 256, 0, stream>>>(lin_edge0, att_edge0, lin_edge1, att_edge1, W0, att_src0,
                                     att_dst0, W1, bias0, time_w, time_b, l0, l1, as0, ad0, W01t,
                                     b01, tab0, tab1);

    // Node features + layer-0 scores + deg/bcnt zeroing
    k_xbs<<<nblk4, 256, 0, stream>>>(x, as0, ad0, xb, ssrc0, sdst0, deg, bcnt);

    // Bucket edges into fixed windows + per-node degree count (fused)
    k_bucketA<<<cbks, 256, 0, stream>>>(ei, ts, deg, bcnt, staging);

    // CSR (self-loop slot reserved at the end of each row)
    k_scan_block<<<nb, 256, 0, stream>>>(deg, rowptr, blocksum, N_NODES);
    k_scan_top<<<1, 256, 0, stream>>>(blocksum, blockoff, nb);
    k_finalize<<<nb, 256, 0, stream>>>(rowptr, blockoff, deg, cursor, edst, esrc, tsp, ssrc0,
                                       sdst0, l0, ew0p);
    k_bucketB<<<NBUCKET, 256, 0, stream>>>(bcnt, staging, cursor, esrc, tsp, ssrc0, sdst0, tab0,
                                           ew0p);

    // Layer 0: aggregate x
    k_aggx<<<nblk16, 256, 0, stream>>>(xb, esrc, ew0p, rowptr, aggx);

    // Layer 1: fused GEMM (W0*W1) + scores, edge weights, aggregate
    k_gemm1s<<<gx, 256, 0, stream>>>(aggx, W01t, b01, att_src1, att_dst1, h1b, ssrc1, sdst1);
    k_ew1<<<ebks, 256, 0, stream>>>(esrc, edst, tsp, tab1, l1, ssrc1, sdst1, ew1p);
    k_agg1<<<nblk32, 256, 0, stream>>>(h1b, esrc, ew1p, rowptr, bias1, out);
}

// Round 18
// 222.167 us; speedup vs baseline: 1.1153x; 1.1153x over previous
//
#include <hip/hip_runtime.h>
#include <math.h>

#define N_NODES 50000
#define N_EDGES 800000
#define ET (N_EDGES + N_NODES)
#define IN_F 128
#define TDIM 64
#define HEADS 4
#define C0 64
#define C1 16
#define HC0 256
#define HC1 64
#define KF 512 /* fused K = 4*IN_F */
#define SLOPE 0.2f
#define TAB 4096
#define BSHIFT 7
#define NBUCKET 391 /* ceil(50000/128) */
#define BCAP 4096   /* staging capacity per bucket (E~2048, sigma~45) */
#define CHUNK 2048  /* edges per block; 391 blocks x 1024 threads */

using short8 = __attribute__((ext_vector_type(8))) short;
using f32x4 = __attribute__((ext_vector_type(4))) float;

__device__ __forceinline__ float bf2f(unsigned u16) { return __uint_as_float(u16 << 16); }
__device__ __forceinline__ unsigned short f2bf(float f) {
    unsigned u = __float_as_uint(f);
    return (unsigned short)((u + 0x7fffu + ((u >> 16) & 1u)) >> 16);
}
__device__ __forceinline__ unsigned pk2(float lo, float hi) {
    return (unsigned)f2bf(lo) | ((unsigned)f2bf(hi) << 16);
}
__device__ __forceinline__ float lrelu(float a) { return a >= 0.f ? a : SLOPE * a; }

// ---------------------------------------------------------------------------
// ALL parameter-only precompute in ONE launch (275 blocks x 256):
//  b == 0        : l0/l1[h] (self-loop logits)
//  b in [1,129)  : as0/ad0[h][k] layer-0 score tables
//  b in [129,257): W01t (bf16 fused W0*W1, transposed)
//  b == 257      : b01 (fused bias)
//  b in [258,275): time-encode tables tab0/tab1 (self-computed v contraction)
__global__ __launch_bounds__(256) void k_param(
    const float* __restrict__ le0, const float* __restrict__ at0, const float* __restrict__ le1,
    const float* __restrict__ at1, const float* __restrict__ W0, const float* __restrict__ asr,
    const float* __restrict__ ads, const float* __restrict__ W1, const float* __restrict__ bias0,
    const float* __restrict__ tw, const float* __restrict__ tb, float* __restrict__ l0,
    float* __restrict__ l1, float* __restrict__ as0, float* __restrict__ ad0,
    unsigned short* __restrict__ W01t, float* __restrict__ b01, float* __restrict__ tab0,
    float* __restrict__ tab1) {
    int b = blockIdx.x, tid = threadIdx.x;
    int h = tid >> 6, c = tid & 63;
    if (b == 0) {
        float s0 = 0.f;
        for (int td = 0; td < TDIM; ++td) s0 += le0[td * HC0 + h * C0 + c];
        s0 *= at0[h * C0 + c];
        for (int m = 1; m < 64; m <<= 1) s0 += __shfl_xor(s0, m);
        if (c == 0) l0[h] = s0;
        float s1 = 0.f;
        if (c < C1) {
            for (int td = 0; td < TDIM; ++td) s1 += le1[td * HC1 + h * C1 + c];
            s1 *= at1[h * C1 + c];
        }
        for (int m = 1; m < 16; m <<= 1) s1 += __shfl_xor(s1, m);
        if (c == 0) l1[h] = s1;
    } else if (b < 129) {
        int k = b - 1;
        float wv = W0[k * HC0 + h * C0 + c];
        float ps = wv * asr[h * C0 + c];
        float pd = wv * ads[h * C0 + c];
        for (int m = 1; m < 64; m <<= 1) {
            ps += __shfl_xor(ps, m);
            pd += __shfl_xor(pd, m);
        }
        if (c == 0) {
            as0[h * IN_F + k] = ps;
            ad0[h * IN_F + k] = pd;
        }
    } else if (b < 257) {
        int hk = (b - 129) * 4 + (tid >> 6);
        int c1 = tid & 63;
        int hh = hk >> 7, k = hk & 127;
        float acc = 0.f;
        for (int c0 = 0; c0 < C0; ++c0)
            acc += W0[k * HC0 + hh * C0 + c0] * W1[(size_t)(hh * C0 + c0) * HC1 + c1];
        W01t[(size_t)c1 * KF + hk] = f2bf(acc);
    } else if (b == 257) {
        if (tid < 64) {
            float acc = 0.f;
            for (int k = 0; k < HC0; ++k) acc += bias0[k] * W1[(size_t)k * HC1 + tid];
            b01[tid] = acc;
        }
    } else {
        // time-encode table blocks: self-compute v contraction in LDS
        __shared__ float sv0[TDIM * 4], sv1[TDIM * 4], sw[TDIM], sb[TDIM];
        int td = tid >> 2, hh = tid & 3;
        float v0l = 0.f;
        for (int c0 = 0; c0 < C0; ++c0) v0l += le0[td * HC0 + hh * C0 + c0] * at0[hh * C0 + c0];
        sv0[td * 4 + hh] = v0l;
        float v1l = 0.f;
        for (int c0 = 0; c0 < C1; ++c0) v1l += le1[td * HC1 + hh * C1 + c0] * at1[hh * C1 + c0];
        sv1[td * 4 + hh] = v1l;
        if (tid < TDIM) {
            sw[tid] = tw[tid];
            sb[tid] = tb[tid];
        }
        __syncthreads();
        int i = (b - 258) * 256 + tid;
        if (i > TAB) return;
        float time = (float)i / (float)TAB;
        float a00 = 0, a01 = 0, a02 = 0, a03 = 0, a10 = 0, a11 = 0, a12 = 0, a13 = 0;
#pragma unroll 8
        for (int d = 0; d < TDIM; ++d) {
            float f = fabsf(__cosf(time * sw[d] + sb[d]));
            a00 += f * sv0[d * 4 + 0];
            a01 += f * sv0[d * 4 + 1];
            a02 += f * sv0[d * 4 + 2];
            a03 += f * sv0[d * 4 + 3];
            a10 += f * sv1[d * 4 + 0];
            a11 += f * sv1[d * 4 + 1];
            a12 += f * sv1[d * 4 + 2];
            a13 += f * sv1[d * 4 + 3];
        }
        ((float4*)tab0)[i] = make_float4(a00, a01, a02, a03);
        ((float4*)tab1)[i] = make_float4(a10, a11, a12, a13);
    }
}

// ---------------------------------------------------------------------------
// Fused x->bf16 + layer-0 scores + deg/bcnt zeroing. One wave per node.
__global__ __launch_bounds__(256) void k_xbs(const float* __restrict__ x,
                                             const float* __restrict__ as0,
                                             const float* __restrict__ ad0,
                                             unsigned short* __restrict__ xb,
                                             float* __restrict__ ssrc, float* __restrict__ sdst,
                                             int* __restrict__ deg, int* __restrict__ bcnt) {
    if (blockIdx.x < 196) {
        int i = blockIdx.x * 256 + threadIdx.x;
        if (i < N_NODES) deg[i] = 0;
    }
    if (blockIdx.x >= 196 && blockIdx.x < 198) {
        int i = (blockIdx.x - 196) * 256 + threadIdx.x;
        if (i < NBUCKET) bcnt[i] = 0;
    }
    int w = threadIdx.x >> 6, l = threadIdx.x & 63;
    int n = blockIdx.x * 4 + w;
    if (n >= N_NODES) return;
    float2 xv = *(const float2*)(x + (size_t)n * IN_F + l * 2);
    *(unsigned*)(xb + (size_t)n * IN_F + l * 2) = pk2(xv.x, xv.y);
    float ps[4], pd[4];
#pragma unroll
    for (int h = 0; h < 4; ++h) {
        float2 a = *(const float2*)(as0 + h * IN_F + l * 2);
        float2 d = *(const float2*)(ad0 + h * IN_F + l * 2);
        ps[h] = xv.x * a.x + xv.y * a.y;
        pd[h] = xv.x * d.x + xv.y * d.y;
    }
#pragma unroll
    for (int m = 1; m < 64; m <<= 1) {
#pragma unroll
        for (int h = 0; h < 4; ++h) {
            ps[h] += __shfl_xor(ps[h], m);
            pd[h] += __shfl_xor(pd[h], m);
        }
    }
    if (l == 0) {
#pragma unroll
        for (int h = 0; h < 4; ++h) {
            ssrc[n * 4 + h] = ps[h];
            sdst[n * 4 + h] = pd[h];
        }
    }
}

// ---------------------------------------------------------------------------
// Phase A: bucket edges by dst>>7 into FIXED per-bucket staging windows
// (b*BCAP) AND count per-node degrees. 391 blocks x 1024 threads (16 waves):
// same per-block bucket-management overhead as the proven 256-thread version
// but 4x the latency-hiding waves. Staging packed int2:
//   .x = (src<<7) | (dst & 127), .y = ts bits
__global__ __launch_bounds__(1024) void k_bucketA(const int* __restrict__ ei,
                                                  const float* __restrict__ ts,
                                                  int* __restrict__ deg, int* __restrict__ bcnt,
                                                  int2* __restrict__ staging) {
    __shared__ int cnt[NBUCKET], base[NBUCKET];
    int tid = threadIdx.x;
    int e0 = blockIdx.x * CHUNK;
    for (int i = tid; i < NBUCKET; i += 1024) cnt[i] = 0;
    __syncthreads();
    int key[2], b[2], tv[2];
#pragma unroll
    for (int i = 0; i < 2; ++i) {
        int tt = e0 + i * 1024 + tid;
        if (tt < N_EDGES) {
            int s = ei[tt];
            int d = ei[N_EDGES + tt];
            key[i] = (s << BSHIFT) | (d & ((1 << BSHIFT) - 1));
            b[i] = d >> BSHIFT;
            tv[i] = __float_as_int(ts[tt]);
            atomicAdd(&cnt[b[i]], 1);
            atomicAdd(&deg[d], 1);  // fused per-node degree count
        } else {
            b[i] = -1;
        }
    }
    __syncthreads();
    for (int i = tid; i < NBUCKET; i += 1024) {
        int c = cnt[i];
        base[i] = c ? atomicAdd(&bcnt[i], c) : 0;
        cnt[i] = 0;  // reuse as running cursor
    }
    __syncthreads();
#pragma unroll
    for (int i = 0; i < 2; ++i) {
        if (b[i] >= 0) {
            int off = atomicAdd(&cnt[b[i]], 1);
            staging[(size_t)b[i] * BCAP + base[b[i]] + off] = make_int2(key[i], tv[i]);
        }
    }
}

// ---------------------------------------------------------------------------
// Hierarchical scan (multi-block). deg+1 = reserved self-loop slot per row.
__global__ void k_scan_block(const int* __restrict__ deg, int* __restrict__ rowptr,
                             int* __restrict__ blocksum, int n) {
    __shared__ int buf[256];
    int tid = threadIdx.x, i = blockIdx.x * 256 + tid;
    int v = (i < n) ? (deg[i] + 1) : 0;
    buf[tid] = v;
    __syncthreads();
    for (int off = 1; off < 256; off <<= 1) {
        int t = (tid >= off) ? buf[tid - off] : 0;
        __syncthreads();
        buf[tid] += t;
        __syncthreads();
    }
    if (i < n) rowptr[i + 1] = buf[tid];
    if (tid == 255) blocksum[blockIdx.x] = buf[255];
}

__global__ void k_scan_top(const int* __restrict__ blocksum, int* __restrict__ blockoff, int nb) {
    __shared__ int buf[256];
    int tid = threadIdx.x;
    int v = (tid < nb) ? blocksum[tid] : 0;
    buf[tid] = v;
    __syncthreads();
    for (int off = 1; off < 256; off <<= 1) {
        int t = (tid >= off) ? buf[tid - off] : 0;
        __syncthreads();
        buf[tid] += t;
        __syncthreads();
    }
    if (tid < nb) blockoff[tid] = buf[tid] - v;  // exclusive
}

// Finalize: rowptr += blockoff; cursor, edst spans (incl. self-loop slot),
// self-loop esrc/tsp/ew0p.
__global__ void k_finalize(int* __restrict__ rowptr, const int* __restrict__ blockoff,
                           const int* __restrict__ deg, int* __restrict__ cursor,
                           int* __restrict__ edst, int* __restrict__ esrc,
                           float* __restrict__ tsp, const float* __restrict__ ssrc0,
                           const float* __restrict__ sdst0, const float* __restrict__ l0,
                           float* __restrict__ ew0p) {
    int i = blockIdx.x * 256 + threadIdx.x;
    if (i >= N_NODES) return;
    int v = rowptr[i + 1] + blockoff[blockIdx.x];
    rowptr[i + 1] = v;
    int start = v - deg[i] - 1;
    cursor[i] = start;
    if (i == 0) rowptr[0] = 0;
    for (int p = start; p < v; ++p) edst[p] = i;  // includes self-loop slot
    esrc[v - 1] = i;                              // self-loop src
    tsp[v - 1] = -1.f;                            // self-loop sentinel
    float4 lv = ((const float4*)l0)[0];
    float4 sv = ((const float4*)ssrc0)[i];
    float4 dv = ((const float4*)sdst0)[i];
    float4 w;
    w.x = __expf(lrelu(sv.x + dv.x + lv.x));
    w.y = __expf(lrelu(sv.y + dv.y + lv.y));
    w.z = __expf(lrelu(sv.z + dv.z + lv.z));
    w.w = __expf(lrelu(sv.w + dv.w + lv.w));
    ((float4*)ew0p)[v - 1] = w;
}

// ---------------------------------------------------------------------------
// Phase B: one block per bucket; scatter from fixed staging window into final
// CSR slots (L2-hot) AND compute layer-0 edge softmax weights (edge-parallel).
__global__ __launch_bounds__(256) void k_bucketB(
    const int* __restrict__ bcnt, const int2* __restrict__ staging, int* __restrict__ cursor,
    int* __restrict__ esrc, float* __restrict__ tsp, const float* __restrict__ ssrc0,
    const float* __restrict__ sdst0, const float* __restrict__ tab0, float* __restrict__ ew0p) {
    int b = blockIdx.x;
    int hi = bcnt[b];
    const int2* win = staging + (size_t)b * BCAP;
    for (int p = threadIdx.x; p < hi; p += 256) {
        int2 kt = win[p];
        int s = ((unsigned)kt.x) >> BSHIFT;
        int d = (b << BSHIFT) | (kt.x & ((1 << BSHIFT) - 1));
        int q = atomicAdd(&cursor[d], 1);
        esrc[q] = s;
        float tv = __int_as_float(kt.y);
        tsp[q] = tv;
        float f = tv * (float)TAB;
        int i = (int)f;
        i = i > TAB - 1 ? TAB - 1 : i;
        float fr = f - (float)i;
        float4 t0 = ((const float4*)tab0)[i];
        float4 t1 = ((const float4*)tab0)[i + 1];
        float4 sv = ((const float4*)ssrc0)[s];
        float4 dv = ((const float4*)sdst0)[d];
        float4 w;
        w.x = __expf(lrelu(sv.x + dv.x + t0.x + fr * (t1.x - t0.x)));
        w.y = __expf(lrelu(sv.y + dv.y + t0.y + fr * (t1.y - t0.y)));
        w.z = __expf(lrelu(sv.z + dv.z + t0.z + fr * (t1.z - t0.z)));
        w.w = __expf(lrelu(sv.w + dv.w + t0.w + fr * (t1.w - t0.w)));
        ((float4*)ew0p)[q] = w;
    }
}

// ---------------------------------------------------------------------------
// Layer-1 edge weights (edge-parallel, streaming, table lerp).
__global__ void k_ew1(const int* __restrict__ esrc, const int* __restrict__ edst,
                      const float* __restrict__ tsp, const float* __restrict__ tab1,
                      const float* __restrict__ l1, const float* __restrict__ ssrc,
                      const float* __restrict__ sdst, float* __restrict__ ew1p) {
    int p = blockIdx.x * blockDim.x + threadIdx.x;
    if (p >= ET) return;
    float tv = tsp[p];
    float4 av;
    if (tv < 0.f) {
        av = ((const float4*)l1)[0];
    } else {
        float f = tv * (float)TAB;
        int i = (int)f;
        i = i > TAB - 1 ? TAB - 1 : i;
        float fr = f - (float)i;
        float4 t0 = ((const float4*)tab1)[i];
        float4 t1 = ((const float4*)tab1)[i + 1];
        av.x = t0.x + fr * (t1.x - t0.x);
        av.y = t0.y + fr * (t1.y - t0.y);
        av.z = t0.z + fr * (t1.z - t0.z);
        av.w = t0.w + fr * (t1.w - t0.w);
    }
    int s = esrc[p], d = edst[p];
    float4 sv = ((const float4*)ssrc)[s];
    float4 dv = ((const float4*)sdst)[d];
    float4 w;
    w.x = __expf(lrelu(sv.x + dv.x + av.x));
    w.y = __expf(lrelu(sv.y + dv.y + av.y));
    w.z = __expf(lrelu(sv.z + dv.z + av.z));
    w.w = __expf(lrelu(sv.w + dv.w + av.w));
    ((float4*)ew1p)[p] = w;
}

// ---------------------------------------------------------------------------
// Layer-0 aggregation of x, precomputed weights, software-pipelined gather.
// 4 nodes per wave (16-lane groups), lane owns 8 channels (all 4 heads).
__global__ __launch_bounds__(256) void k_aggx(const unsigned short* __restrict__ xb,
                                              const int* __restrict__ esrc,
                                              const float* __restrict__ ew0p,
                                              const int* __restrict__ rowptr,
                                              unsigned short* __restrict__ aggx) {
    int grp = threadIdx.x >> 4, lo = threadIdx.x & 15;
    int n = blockIdx.x * 16 + grp;
    if (n >= N_NODES) return;
    int p0 = rowptr[n], p1 = rowptr[n + 1];  // p1 > p0 always (self-loop)
    float acc[4][8];
#pragma unroll
    for (int h = 0; h < 4; ++h)
#pragma unroll
        for (int j = 0; j < 8; ++j) acc[h][j] = 0.f;
    float ss0 = 0, ss1 = 0, ss2 = 0, ss3 = 0;
    float4 e_cur = ((const float4*)ew0p)[p0];
    uint4 x_cur = *(const uint4*)(xb + (size_t)esrc[p0] * IN_F + lo * 8);
    int s_nxt = (p0 + 1 < p1) ? esrc[p0 + 1] : 0;
    for (int p = p0; p < p1; ++p) {
        float4 e = e_cur;
        uint4 xv = x_cur;
        if (p + 1 < p1) {
            e_cur = ((const float4*)ew0p)[p + 1];
            x_cur = *(const uint4*)(xb + (size_t)s_nxt * IN_F + lo * 8);
            if (p + 2 < p1) s_nxt = esrc[p + 2];
        }
        float f[8];
        f[0] = bf2f(xv.x & 0xffff);
        f[1] = bf2f(xv.x >> 16);
        f[2] = bf2f(xv.y & 0xffff);
        f[3] = bf2f(xv.y >> 16);
        f[4] = bf2f(xv.z & 0xffff);
        f[5] = bf2f(xv.z >> 16);
        f[6] = bf2f(xv.w & 0xffff);
        f[7] = bf2f(xv.w >> 16);
#pragma unroll
        for (int j = 0; j < 8; ++j) {
            acc[0][j] += e.x * f[j];
            acc[1][j] += e.y * f[j];
            acc[2][j] += e.z * f[j];
            acc[3][j] += e.w * f[j];
        }
        ss0 += e.x;
        ss1 += e.y;
        ss2 += e.z;
        ss3 += e.w;
    }
    float inv[4] = {1.f / (ss0 + 1e-16f), 1.f / (ss1 + 1e-16f), 1.f / (ss2 + 1e-16f),
                    1.f / (ss3 + 1e-16f)};
    size_t base = (size_t)n * KF + lo * 8;
#pragma unroll
    for (int h = 0; h < 4; ++h) {
        uint4 r;
        r.x = pk2(acc[h][0] * inv[h], acc[h][1] * inv[h]);
        r.y = pk2(acc[h][2] * inv[h], acc[h][3] * inv[h]);
        r.z = pk2(acc[h][4] * inv[h], acc[h][5] * inv[h]);
        r.w = pk2(acc[h][6] * inv[h], acc[h][7] * inv[h]);
        *(uint4*)(aggx + base + h * IN_F) = r;
    }
}

// ---------------------------------------------------------------------------
// h1 = aggx @ W01t^T + b01 ; writes h1b (bf16) + fused layer-1 scores
// (epilogue lives here: compute-bound kernel, registers are cheap).
__global__ __launch_bounds__(256) void k_gemm1s(
    const unsigned short* __restrict__ A, const unsigned short* __restrict__ Bt,
    const float* __restrict__ b01, const float* __restrict__ a_src,
    const float* __restrict__ a_dst, unsigned short* __restrict__ h1b, float* __restrict__ ssrc,
    float* __restrict__ sdst) {
    __shared__ unsigned short As[128 * 40];
    __shared__ unsigned short Bs[64 * 40];
    int tid = threadIdx.x, w = tid >> 6, l = tid & 63, lo = l & 15, hi = l >> 4;
    int m0 = blockIdx.x * 128;
    f32x4 acc[2][4];
#pragma unroll
    for (int i = 0; i < 2; ++i)
#pragma unroll
        for (int j = 0; j < 4; ++j) acc[i][j] = (f32x4){0.f, 0.f, 0.f, 0.f};
    int arow4 = tid >> 2, aseg = tid & 3;
    for (int k0 = 0; k0 < KF; k0 += 32) {
#pragma unroll
        for (int hf = 0; hf < 2; ++hf) {
            int arow = hf * 64 + arow4;
            uint4 va = {0, 0, 0, 0};
            if (m0 + arow < N_NODES)
                va = *(const uint4*)(A + (size_t)(m0 + arow) * KF + k0 + aseg * 8);
            *(uint4*)&As[arow * 40 + aseg * 8] = va;
        }
        uint4 vb = *(const uint4*)(Bt + (size_t)arow4 * KF + k0 + aseg * 8);
        *(uint4*)&Bs[arow4 * 40 + aseg * 8] = vb;
        __syncthreads();
        short8 af[2], bf[4];
#pragma unroll
        for (int fa = 0; fa < 2; ++fa)
            af[fa] = *(const short8*)&As[(w * 32 + fa * 16 + lo) * 40 + hi * 8];
#pragma unroll
        for (int nf = 0; nf < 4; ++nf) bf[nf] = *(const short8*)&Bs[(nf * 16 + lo) * 40 + hi * 8];
#pragma unroll
        for (int fa = 0; fa < 2; ++fa)
#pragma unroll
            for (int nf = 0; nf < 4; ++nf)
                acc[fa][nf] =
                    __builtin_amdgcn_mfma_f32_16x16x32_bf16(af[fa], bf[nf], acc[fa][nf], 0, 0, 0);
        __syncthreads();
    }
    float asv[4], adv[4], bv[4];
#pragma unroll
    for (int nf = 0; nf < 4; ++nf) {
        asv[nf] = a_src[nf * 16 + lo];
        adv[nf] = a_dst[nf * 16 + lo];
        bv[nf] = b01[nf * 16 + lo];
    }
#pragma unroll
    for (int fa = 0; fa < 2; ++fa)
#pragma unroll
        for (int r = 0; r < 4; ++r) {
            int row = m0 + w * 32 + fa * 16 + hi * 4 + r;
#pragma unroll
            for (int nf = 0; nf < 4; ++nf) {
                float v = acc[fa][nf][r] + bv[nf];
                if (row < N_NODES) h1b[(size_t)row * HC1 + nf * 16 + lo] = f2bf(v);
                float ps = v * asv[nf], pd = v * adv[nf];
                for (int m = 1; m < 16; m <<= 1) {
                    ps += __shfl_xor(ps, m);
                    pd += __shfl_xor(pd, m);
                }
                if (lo == 0 && row < N_NODES) {
                    ssrc[row * 4 + nf] = ps;
                    sdst[row * 4 + nf] = pd;
                }
            }
        }
}

// ---------------------------------------------------------------------------
// Layer-1 aggregation: 8-lane groups (8 gather chains/wave), lane owns 8
// channels (one uint4 16B load), head = lo>>1. 2-deep esrc prefetch.
// Final output stored non-temporal (never re-read).
__global__ __launch_bounds__(256) void k_agg1(
    const unsigned short* __restrict__ h1b, const int* __restrict__ esrc,
    const float* __restrict__ ew1p, const int* __restrict__ rowptr,
    const float* __restrict__ bias, float* __restrict__ out) {
    int grp = threadIdx.x >> 3, lo = threadIdx.x & 7;
    int n = blockIdx.x * 32 + grp;
    if (n >= N_NODES) return;
    int head = lo >> 1;
    int p0 = rowptr[n], p1 = rowptr[n + 1];
    float a0 = 0, a1 = 0, a2 = 0, a3 = 0, a4 = 0, a5 = 0, a6 = 0, a7 = 0, ss = 0;
    float e_cur = ew1p[p0 * 4 + head];
    uint4 h_cur = *(const uint4*)(h1b + (size_t)esrc[p0] * HC1 + lo * 8);
    int s_nxt = (p0 + 1 < p1) ? esrc[p0 + 1] : 0;
    for (int p = p0; p < p1; ++p) {
        float e = e_cur;
        uint4 hv = h_cur;
        if (p + 1 < p1) {
            e_cur = ew1p[(p + 1) * 4 + head];
            h_cur = *(const uint4*)(h1b + (size_t)s_nxt * HC1 + lo * 8);
            if (p + 2 < p1) s_nxt = esrc[p + 2];
        }
        a0 += e * bf2f(hv.x & 0xffff);
        a1 += e * bf2f(hv.x >> 16);
        a2 += e * bf2f(hv.y & 0xffff);
        a3 += e * bf2f(hv.y >> 16);
        a4 += e * bf2f(hv.z & 0xffff);
        a5 += e * bf2f(hv.z >> 16);
        a6 += e * bf2f(hv.w & 0xffff);
        a7 += e * bf2f(hv.w >> 16);
        ss += e;
    }
    float inv = 1.f / (ss + 1e-16f);
    float4 b0 = *(const float4*)(bias + lo * 8);
    float4 b1 = *(const float4*)(bias + lo * 8 + 4);
    size_t o = (size_t)n * HC1 + lo * 8;
    float4 r0 = make_float4(a0 * inv + b0.x, a1 * inv + b0.y, a2 * inv + b0.z, a3 * inv + b0.w);
    float4 r1 = make_float4(a4 * inv + b1.x, a5 * inv + b1.y, a6 * inv + b1.z, a7 * inv + b1.w);
    float* po = out + o;
    __builtin_nontemporal_store(r0.x, po + 0);
    __builtin_nontemporal_store(r0.y, po + 1);
    __builtin_nontemporal_store(r0.z, po + 2);
    __builtin_nontemporal_store(r0.w, po + 3);
    __builtin_nontemporal_store(r1.x, po + 4);
    __builtin_nontemporal_store(r1.y, po + 5);
    __builtin_nontemporal_store(r1.z, po + 6);
    __builtin_nontemporal_store(r1.w, po + 7);
}

// ---------------------------------------------------------------------------
extern "C" void kernel_launch(void* const* d_in, const int* in_sizes, int n_in, void* d_out,
                              int out_size, void* d_ws, size_t ws_size, hipStream_t stream) {
    const float* x = (const float*)d_in[0];
    const int* ei = (const int*)d_in[1];
    const float* ts = (const float*)d_in[2];
    const float* time_w = (const float*)d_in[3];
    const float* time_b = (const float*)d_in[4];
    const float* W0 = (const float*)d_in[5];
    const float* att_src0 = (const float*)d_in[6];
    const float* att_dst0 = (const float*)d_in[7];
    const float* lin_edge0 = (const float*)d_in[8];
    const float* att_edge0 = (const float*)d_in[9];
    const float* bias0 = (const float*)d_in[10];
    const float* W1 = (const float*)d_in[11];
    const float* att_src1 = (const float*)d_in[12];
    const float* att_dst1 = (const float*)d_in[13];
    const float* lin_edge1 = (const float*)d_in[14];
    const float* att_edge1 = (const float*)d_in[15];
    const float* bias1 = (const float*)d_in[16];
    float* out = (float*)d_out;

    char* ws = (char*)d_ws;
    size_t off = 0;
    auto alloc = [&](size_t bytes) -> void* {
        void* p = ws + off;
        off = (off + bytes + 255) & ~(size_t)255;
        return p;
    };
    unsigned short* xb = (unsigned short*)alloc((size_t)N_NODES * IN_F * 2);
    unsigned short* aggx = (unsigned short*)alloc((size_t)N_NODES * KF * 2);
    unsigned short* h1b = (unsigned short*)alloc((size_t)N_NODES * HC1 * 2);
    unsigned short* W01t = (unsigned short*)alloc((size_t)HC1 * KF * 2);
    float* b01 = (float*)alloc(HC1 * 4);
    float* as0 = (float*)alloc(4 * IN_F * 4);
    float* ad0 = (float*)alloc(4 * IN_F * 4);
    float* tab0 = (float*)alloc((size_t)(TAB + 1) * 4 * 4);
    float* tab1 = (float*)alloc((size_t)(TAB + 1) * 4 * 4);
    float* ew0p = (float*)alloc((size_t)ET * 4 * 4);
    float* ew1p = (float*)alloc((size_t)ET * 4 * 4);
    float* ssrc0 = (float*)alloc((size_t)N_NODES * 4 * 4);
    float* sdst0 = (float*)alloc((size_t)N_NODES * 4 * 4);
    float* ssrc1 = (float*)alloc((size_t)N_NODES * 4 * 4);
    float* sdst1 = (float*)alloc((size_t)N_NODES * 4 * 4);
    float* l0 = (float*)alloc(16);
    float* l1 = (float*)alloc(16);
    float* tsp = (float*)alloc((size_t)ET * 4);
    int* deg = (int*)alloc((size_t)N_NODES * 4);
    int* rowptr = (int*)alloc((size_t)(N_NODES + 1) * 4);
    int* cursor = (int*)alloc((size_t)(N_NODES + 1) * 4);
    int* blocksum = (int*)alloc(256 * 4);
    int* blockoff = (int*)alloc(256 * 4);
    int* bcnt = (int*)alloc(NBUCKET * 4);
    int2* staging = (int2*)alloc((size_t)NBUCKET * BCAP * 8);
    int* esrc = (int*)alloc((size_t)ET * 4);
    int* edst = (int*)alloc((size_t)ET * 4);
    (void)ws_size;
    (void)in_sizes;
    (void)n_in;
    (void)out_size;

    int nb = (N_NODES + 255) / 256;            // 196
    int ebks = (ET + 255) / 256;               // 3321
    int cbks = (N_EDGES + CHUNK - 1) / CHUNK;  // 391
    int gx = (N_NODES + 127) / 128;            // 391
    int nblk16 = (N_NODES + 15) / 16;          // 3125
    int nblk32 = (N_NODES + 31) / 32;          // 1563
    int nblk4 = (N_NODES + 3) / 4;             // 12500

    // Parameter-only precompute (single launch, incl. time-encode tables)
    k_param<<<275, 256, 0, stream>>>(lin_edge0, att_edge0, lin_edge1, att_edge1, W0, att_src0,
                                     att_dst0, W1, bias0, time_w, time_b, l0, l1, as0, ad0, W01t,
                                     b01, tab0, tab1);

    // Node features + layer-0 scores + deg/bcnt zeroing
    k_xbs<<<nblk4, 256, 0, stream>>>(x, as0, ad0, xb, ssrc0, sdst0, deg, bcnt);

    // Bucket edges into fixed windows + per-node degree count (fused)
    k_bucketA<<<cbks, 1024, 0, stream>>>(ei, ts, deg, bcnt, staging);

    // CSR (self-loop slot reserved at the end of each row)
    k_scan_block<<<nb, 256, 0, stream>>>(deg, rowptr, blocksum, N_NODES);
    k_scan_top<<<1, 256, 0, stream>>>(blocksum, blockoff, nb);
    k_finalize<<<nb, 256, 0, stream>>>(rowptr, blockoff, deg, cursor, edst, esrc, tsp, ssrc0,
                                       sdst0, l0, ew0p);
    k_bucketB<<<NBUCKET, 256, 0, stream>>>(bcnt, staging, cursor, esrc, tsp, ssrc0, sdst0, tab0,
                                           ew0p);

    // Layer 0: aggregate x
    k_aggx<<<nblk16, 256, 0, stream>>>(xb, esrc, ew0p, rowptr, aggx);

    // Layer 1: fused GEMM (W0*W1) + scores, edge weights, aggregate
    k_gemm1s<<<gx, 256, 0, stream>>>(aggx, W01t, b01, att_src1, att_dst1, h1b, ssrc1, sdst1);
    k_ew1<<<ebks, 256, 0, stream>>>(esrc, edst, tsp, tab1, l1, ssrc1, sdst1, ew1p);
    k_agg1<<<nblk32, 256, 0, stream>>>(h1b, esrc, ew1p, rowptr, bias1, out);
}

// Round 19
// 219.474 us; speedup vs baseline: 1.1289x; 1.0123x over previous
//
#include <hip/hip_runtime.h>
#include <math.h>

#define N_NODES 50000
#define N_EDGES 800000
#define ET (N_EDGES + N_NODES)
#define IN_F 128
#define TDIM 64
#define HEADS 4
#define C0 64
#define C1 16
#define HC0 256
#define HC1 64
#define KF 512 /* fused K = 4*IN_F */
#define SLOPE 0.2f
#define TAB 4096
#define BSHIFT 7
#define NBUCKET 391 /* ceil(50000/128) */
#define BCAP 4096   /* staging capacity per bucket (E~2048, sigma~45) */
#define CHUNK 4096  /* edges per block; 196 blocks x 1024 threads */

using short8 = __attribute__((ext_vector_type(8))) short;
using f32x4 = __attribute__((ext_vector_type(4))) float;

__device__ __forceinline__ float bf2f(unsigned u16) { return __uint_as_float(u16 << 16); }
__device__ __forceinline__ unsigned short f2bf(float f) {
    unsigned u = __float_as_uint(f);
    return (unsigned short)((u + 0x7fffu + ((u >> 16) & 1u)) >> 16);
}
__device__ __forceinline__ unsigned pk2(float lo, float hi) {
    return (unsigned)f2bf(lo) | ((unsigned)f2bf(hi) << 16);
}
__device__ __forceinline__ float lrelu(float a) { return a >= 0.f ? a : SLOPE * a; }

// ---------------------------------------------------------------------------
// ALL parameter-only precompute in ONE launch (275 blocks x 256).
__global__ __launch_bounds__(256) void k_param(
    const float* __restrict__ le0, const float* __restrict__ at0, const float* __restrict__ le1,
    const float* __restrict__ at1, const float* __restrict__ W0, const float* __restrict__ asr,
    const float* __restrict__ ads, const float* __restrict__ W1, const float* __restrict__ bias0,
    const float* __restrict__ tw, const float* __restrict__ tb, float* __restrict__ l0,
    float* __restrict__ l1, float* __restrict__ as0, float* __restrict__ ad0,
    unsigned short* __restrict__ W01t, float* __restrict__ b01, float* __restrict__ tab0,
    float* __restrict__ tab1) {
    int b = blockIdx.x, tid = threadIdx.x;
    int h = tid >> 6, c = tid & 63;
    if (b == 0) {
        float s0 = 0.f;
        for (int td = 0; td < TDIM; ++td) s0 += le0[td * HC0 + h * C0 + c];
        s0 *= at0[h * C0 + c];
        for (int m = 1; m < 64; m <<= 1) s0 += __shfl_xor(s0, m);
        if (c == 0) l0[h] = s0;
        float s1 = 0.f;
        if (c < C1) {
            for (int td = 0; td < TDIM; ++td) s1 += le1[td * HC1 + h * C1 + c];
            s1 *= at1[h * C1 + c];
        }
        for (int m = 1; m < 16; m <<= 1) s1 += __shfl_xor(s1, m);
        if (c == 0) l1[h] = s1;
    } else if (b < 129) {
        int k = b - 1;
        float wv = W0[k * HC0 + h * C0 + c];
        float ps = wv * asr[h * C0 + c];
        float pd = wv * ads[h * C0 + c];
        for (int m = 1; m < 64; m <<= 1) {
            ps += __shfl_xor(ps, m);
            pd += __shfl_xor(pd, m);
        }
        if (c == 0) {
            as0[h * IN_F + k] = ps;
            ad0[h * IN_F + k] = pd;
        }
    } else if (b < 257) {
        int hk = (b - 129) * 4 + (tid >> 6);
        int c1 = tid & 63;
        int hh = hk >> 7, k = hk & 127;
        float acc = 0.f;
        for (int c0 = 0; c0 < C0; ++c0)
            acc += W0[k * HC0 + hh * C0 + c0] * W1[(size_t)(hh * C0 + c0) * HC1 + c1];
        W01t[(size_t)c1 * KF + hk] = f2bf(acc);
    } else if (b == 257) {
        if (tid < 64) {
            float acc = 0.f;
            for (int k = 0; k < HC0; ++k) acc += bias0[k] * W1[(size_t)k * HC1 + tid];
            b01[tid] = acc;
        }
    } else {
        // time-encode table blocks: self-compute v contraction in LDS
        __shared__ float sv0[TDIM * 4], sv1[TDIM * 4], sw[TDIM], sb[TDIM];
        int td = tid >> 2, hh = tid & 3;
        float v0l = 0.f;
        for (int c0 = 0; c0 < C0; ++c0) v0l += le0[td * HC0 + hh * C0 + c0] * at0[hh * C0 + c0];
        sv0[td * 4 + hh] = v0l;
        float v1l = 0.f;
        for (int c0 = 0; c0 < C1; ++c0) v1l += le1[td * HC1 + hh * C1 + c0] * at1[hh * C1 + c0];
        sv1[td * 4 + hh] = v1l;
        if (tid < TDIM) {
            sw[tid] = tw[tid];
            sb[tid] = tb[tid];
        }
        __syncthreads();
        int i = (b - 258) * 256 + tid;
        if (i > TAB) return;
        float time = (float)i / (float)TAB;
        float a00 = 0, a01 = 0, a02 = 0, a03 = 0, a10 = 0, a11 = 0, a12 = 0, a13 = 0;
#pragma unroll 8
        for (int d = 0; d < TDIM; ++d) {
            float f = fabsf(__cosf(time * sw[d] + sb[d]));
            a00 += f * sv0[d * 4 + 0];
            a01 += f * sv0[d * 4 + 1];
            a02 += f * sv0[d * 4 + 2];
            a03 += f * sv0[d * 4 + 3];
            a10 += f * sv1[d * 4 + 0];
            a11 += f * sv1[d * 4 + 1];
            a12 += f * sv1[d * 4 + 2];
            a13 += f * sv1[d * 4 + 3];
        }
        ((float4*)tab0)[i] = make_float4(a00, a01, a02, a03);
        ((float4*)tab1)[i] = make_float4(a10, a11, a12, a13);
    }
}

// ---------------------------------------------------------------------------
// Fused x->bf16 + layer-0 scores + deg/bcnt zeroing. One wave per node.
__global__ __launch_bounds__(256) void k_xbs(const float* __restrict__ x,
                                             const float* __restrict__ as0,
                                             const float* __restrict__ ad0,
                                             unsigned short* __restrict__ xb,
                                             float* __restrict__ ssrc, float* __restrict__ sdst,
                                             int* __restrict__ deg, int* __restrict__ bcnt) {
    if (blockIdx.x < 196) {
        int i = blockIdx.x * 256 + threadIdx.x;
        if (i < N_NODES) deg[i] = 0;
    }
    if (blockIdx.x >= 196 && blockIdx.x < 198) {
        int i = (blockIdx.x - 196) * 256 + threadIdx.x;
        if (i < NBUCKET) bcnt[i] = 0;
    }
    int w = threadIdx.x >> 6, l = threadIdx.x & 63;
    int n = blockIdx.x * 4 + w;
    if (n >= N_NODES) return;
    float2 xv = *(const float2*)(x + (size_t)n * IN_F + l * 2);
    *(unsigned*)(xb + (size_t)n * IN_F + l * 2) = pk2(xv.x, xv.y);
    float ps[4], pd[4];
#pragma unroll
    for (int h = 0; h < 4; ++h) {
        float2 a = *(const float2*)(as0 + h * IN_F + l * 2);
        float2 d = *(const float2*)(ad0 + h * IN_F + l * 2);
        ps[h] = xv.x * a.x + xv.y * a.y;
        pd[h] = xv.x * d.x + xv.y * d.y;
    }
#pragma unroll
    for (int m = 1; m < 64; m <<= 1) {
#pragma unroll
        for (int h = 0; h < 4; ++h) {
            ps[h] += __shfl_xor(ps[h], m);
            pd[h] += __shfl_xor(pd[h], m);
        }
    }
    if (l == 0) {
#pragma unroll
        for (int h = 0; h < 4; ++h) {
            ssrc[n * 4 + h] = ps[h];
            sdst[n * 4 + h] = pd[h];
        }
    }
}

// ---------------------------------------------------------------------------
// Phase A: bucket edges by dst>>7 into FIXED per-bucket staging windows
// (b*BCAP) AND count per-node degrees. 196 blocks x 1024 threads (16 waves).
// Staging packed int2: .x = (src<<7) | (dst & 127), .y = ts bits
__global__ __launch_bounds__(1024) void k_bucketA(const int* __restrict__ ei,
                                                  const float* __restrict__ ts,
                                                  int* __restrict__ deg, int* __restrict__ bcnt,
                                                  int2* __restrict__ staging) {
    __shared__ int cnt[NBUCKET], base[NBUCKET];
    int tid = threadIdx.x;
    int e0 = blockIdx.x * CHUNK;
    for (int i = tid; i < NBUCKET; i += 1024) cnt[i] = 0;
    __syncthreads();
    int key[4], b[4], tv[4];
#pragma unroll
    for (int i = 0; i < 4; ++i) {
        int tt = e0 + i * 1024 + tid;
        if (tt < N_EDGES) {
            int s = ei[tt];
            int d = ei[N_EDGES + tt];
            key[i] = (s << BSHIFT) | (d & ((1 << BSHIFT) - 1));
            b[i] = d >> BSHIFT;
            tv[i] = __float_as_int(ts[tt]);
            atomicAdd(&cnt[b[i]], 1);
            atomicAdd(&deg[d], 1);  // fused per-node degree count
        } else {
            b[i] = -1;
        }
    }
    __syncthreads();
    for (int i = tid; i < NBUCKET; i += 1024) {
        int c = cnt[i];
        base[i] = c ? atomicAdd(&bcnt[i], c) : 0;
        cnt[i] = 0;  // reuse as running cursor
    }
    __syncthreads();
#pragma unroll
    for (int i = 0; i < 4; ++i) {
        if (b[i] >= 0) {
            int off = atomicAdd(&cnt[b[i]], 1);
            staging[(size_t)b[i] * BCAP + base[b[i]] + off] = make_int2(key[i], tv[i]);
        }
    }
}

// ---------------------------------------------------------------------------
// Hierarchical scan (multi-block). deg+1 = reserved self-loop slot per row.
__global__ void k_scan_block(const int* __restrict__ deg, int* __restrict__ rowptr,
                             int* __restrict__ blocksum, int n) {
    __shared__ int buf[256];
    int tid = threadIdx.x, i = blockIdx.x * 256 + tid;
    int v = (i < n) ? (deg[i] + 1) : 0;
    buf[tid] = v;
    __syncthreads();
    for (int off = 1; off < 256; off <<= 1) {
        int t = (tid >= off) ? buf[tid - off] : 0;
        __syncthreads();
        buf[tid] += t;
        __syncthreads();
    }
    if (i < n) rowptr[i + 1] = buf[tid];
    if (tid == 255) blocksum[blockIdx.x] = buf[255];
}

__global__ void k_scan_top(const int* __restrict__ blocksum, int* __restrict__ blockoff, int nb) {
    __shared__ int buf[256];
    int tid = threadIdx.x;
    int v = (tid < nb) ? blocksum[tid] : 0;
    buf[tid] = v;
    __syncthreads();
    for (int off = 1; off < 256; off <<= 1) {
        int t = (tid >= off) ? buf[tid - off] : 0;
        __syncthreads();
        buf[tid] += t;
        __syncthreads();
    }
    if (tid < nb) blockoff[tid] = buf[tid] - v;  // exclusive
}

// Finalize: rowptr += blockoff; cursor, edst spans (incl. self-loop slot),
// self-loop esrc/tsp/ew0p (packed bf16x4).
__global__ void k_finalize(int* __restrict__ rowptr, const int* __restrict__ blockoff,
                           const int* __restrict__ deg, int* __restrict__ cursor,
                           int* __restrict__ edst, int* __restrict__ esrc,
                           float* __restrict__ tsp, const float* __restrict__ ssrc0,
                           const float* __restrict__ sdst0, const float* __restrict__ l0,
                           unsigned* __restrict__ ew0p) {
    int i = blockIdx.x * 256 + threadIdx.x;
    if (i >= N_NODES) return;
    int v = rowptr[i + 1] + blockoff[blockIdx.x];
    rowptr[i + 1] = v;
    int start = v - deg[i] - 1;
    cursor[i] = start;
    if (i == 0) rowptr[0] = 0;
    for (int p = start; p < v; ++p) edst[p] = i;  // includes self-loop slot
    esrc[v - 1] = i;                              // self-loop src
    tsp[v - 1] = -1.f;                            // self-loop sentinel
    float4 lv = ((const float4*)l0)[0];
    float4 sv = ((const float4*)ssrc0)[i];
    float4 dv = ((const float4*)sdst0)[i];
    float w0 = __expf(lrelu(sv.x + dv.x + lv.x));
    float w1 = __expf(lrelu(sv.y + dv.y + lv.y));
    float w2 = __expf(lrelu(sv.z + dv.z + lv.z));
    float w3 = __expf(lrelu(sv.w + dv.w + lv.w));
    ((uint2*)ew0p)[v - 1] = make_uint2(pk2(w0, w1), pk2(w2, w3));
}

// ---------------------------------------------------------------------------
// Phase B: one block per bucket; scatter from fixed staging window into final
// CSR slots (L2-hot) AND compute layer-0 edge softmax weights (packed bf16x4).
__global__ __launch_bounds__(256) void k_bucketB(
    const int* __restrict__ bcnt, const int2* __restrict__ staging, int* __restrict__ cursor,
    int* __restrict__ esrc, float* __restrict__ tsp, const float* __restrict__ ssrc0,
    const float* __restrict__ sdst0, const float* __restrict__ tab0,
    unsigned* __restrict__ ew0p) {
    int b = blockIdx.x;
    int hi = bcnt[b];
    const int2* win = staging + (size_t)b * BCAP;
    for (int p = threadIdx.x; p < hi; p += 256) {
        int2 kt = win[p];
        int s = ((unsigned)kt.x) >> BSHIFT;
        int d = (b << BSHIFT) | (kt.x & ((1 << BSHIFT) - 1));
        int q = atomicAdd(&cursor[d], 1);
        esrc[q] = s;
        float tv = __int_as_float(kt.y);
        tsp[q] = tv;
        float f = tv * (float)TAB;
        int i = (int)f;
        i = i > TAB - 1 ? TAB - 1 : i;
        float fr = f - (float)i;
        float4 t0 = ((const float4*)tab0)[i];
        float4 t1 = ((const float4*)tab0)[i + 1];
        float4 sv = ((const float4*)ssrc0)[s];
        float4 dv = ((const float4*)sdst0)[d];
        float w0 = __expf(lrelu(sv.x + dv.x + t0.x + fr * (t1.x - t0.x)));
        float w1 = __expf(lrelu(sv.y + dv.y + t0.y + fr * (t1.y - t0.y)));
        float w2 = __expf(lrelu(sv.z + dv.z + t0.z + fr * (t1.z - t0.z)));
        float w3 = __expf(lrelu(sv.w + dv.w + t0.w + fr * (t1.w - t0.w)));
        ((uint2*)ew0p)[q] = make_uint2(pk2(w0, w1), pk2(w2, w3));
    }
}

// ---------------------------------------------------------------------------
// Layer-1 edge weights (edge-parallel, streaming, table lerp, packed bf16x4).
__global__ void k_ew1(const int* __restrict__ esrc, const int* __restrict__ edst,
                      const float* __restrict__ tsp, const float* __restrict__ tab1,
                      const float* __restrict__ l1, const float* __restrict__ ssrc,
                      const float* __restrict__ sdst, unsigned* __restrict__ ew1p) {
    int p = blockIdx.x * blockDim.x + threadIdx.x;
    if (p >= ET) return;
    float tv = tsp[p];
    float4 av;
    if (tv < 0.f) {
        av = ((const float4*)l1)[0];
    } else {
        float f = tv * (float)TAB;
        int i = (int)f;
        i = i > TAB - 1 ? TAB - 1 : i;
        float fr = f - (float)i;
        float4 t0 = ((const float4*)tab1)[i];
        float4 t1 = ((const float4*)tab1)[i + 1];
        av.x = t0.x + fr * (t1.x - t0.x);
        av.y = t0.y + fr * (t1.y - t0.y);
        av.z = t0.z + fr * (t1.z - t0.z);
        av.w = t0.w + fr * (t1.w - t0.w);
    }
    int s = esrc[p], d = edst[p];
    float4 sv = ((const float4*)ssrc)[s];
    float4 dv = ((const float4*)sdst)[d];
    float w0 = __expf(lrelu(sv.x + dv.x + av.x));
    float w1 = __expf(lrelu(sv.y + dv.y + av.y));
    float w2 = __expf(lrelu(sv.z + dv.z + av.z));
    float w3 = __expf(lrelu(sv.w + dv.w + av.w));
    ((uint2*)ew1p)[p] = make_uint2(pk2(w0, w1), pk2(w2, w3));
}

// ---------------------------------------------------------------------------
// Layer-0 aggregation of x, precomputed packed weights, pipelined gather.
// 4 nodes per wave (16-lane groups), lane owns 8 channels (all 4 heads).
__global__ __launch_bounds__(256) void k_aggx(const unsigned short* __restrict__ xb,
                                              const int* __restrict__ esrc,
                                              const unsigned* __restrict__ ew0p,
                                              const int* __restrict__ rowptr,
                                              unsigned short* __restrict__ aggx) {
    int grp = threadIdx.x >> 4, lo = threadIdx.x & 15;
    int n = blockIdx.x * 16 + grp;
    if (n >= N_NODES) return;
    int p0 = rowptr[n], p1 = rowptr[n + 1];  // p1 > p0 always (self-loop)
    float acc[4][8];
#pragma unroll
    for (int h = 0; h < 4; ++h)
#pragma unroll
        for (int j = 0; j < 8; ++j) acc[h][j] = 0.f;
    float ss0 = 0, ss1 = 0, ss2 = 0, ss3 = 0;
    uint2 e_cur = ((const uint2*)ew0p)[p0];
    uint4 x_cur = *(const uint4*)(xb + (size_t)esrc[p0] * IN_F + lo * 8);
    int s_nxt = (p0 + 1 < p1) ? esrc[p0 + 1] : 0;
    for (int p = p0; p < p1; ++p) {
        uint2 ev = e_cur;
        uint4 xv = x_cur;
        if (p + 1 < p1) {
            e_cur = ((const uint2*)ew0p)[p + 1];
            x_cur = *(const uint4*)(xb + (size_t)s_nxt * IN_F + lo * 8);
            if (p + 2 < p1) s_nxt = esrc[p + 2];
        }
        float e0 = bf2f(ev.x & 0xffff), e1 = bf2f(ev.x >> 16);
        float e2 = bf2f(ev.y & 0xffff), e3 = bf2f(ev.y >> 16);
        float f[8];
        f[0] = bf2f(xv.x & 0xffff);
        f[1] = bf2f(xv.x >> 16);
        f[2] = bf2f(xv.y & 0xffff);
        f[3] = bf2f(xv.y >> 16);
        f[4] = bf2f(xv.z & 0xffff);
        f[5] = bf2f(xv.z >> 16);
        f[6] = bf2f(xv.w & 0xffff);
        f[7] = bf2f(xv.w >> 16);
#pragma unroll
        for (int j = 0; j < 8; ++j) {
            acc[0][j] += e0 * f[j];
            acc[1][j] += e1 * f[j];
            acc[2][j] += e2 * f[j];
            acc[3][j] += e3 * f[j];
        }
        ss0 += e0;
        ss1 += e1;
        ss2 += e2;
        ss3 += e3;
    }
    float inv[4] = {1.f / (ss0 + 1e-16f), 1.f / (ss1 + 1e-16f), 1.f / (ss2 + 1e-16f),
                    1.f / (ss3 + 1e-16f)};
    size_t base = (size_t)n * KF + lo * 8;
#pragma unroll
    for (int h = 0; h < 4; ++h) {
        uint4 r;
        r.x = pk2(acc[h][0] * inv[h], acc[h][1] * inv[h]);
        r.y = pk2(acc[h][2] * inv[h], acc[h][3] * inv[h]);
        r.z = pk2(acc[h][4] * inv[h], acc[h][5] * inv[h]);
        r.w = pk2(acc[h][6] * inv[h], acc[h][7] * inv[h]);
        *(uint4*)(aggx + base + h * IN_F) = r;
    }
}

// ---------------------------------------------------------------------------
// h1 = aggx @ W01t^T + b01 ; writes h1b (bf16) + fused layer-1 scores
// (epilogue lives here: compute-bound kernel, registers are cheap).
__global__ __launch_bounds__(256) void k_gemm1s(
    const unsigned short* __restrict__ A, const unsigned short* __restrict__ Bt,
    const float* __restrict__ b01, const float* __restrict__ a_src,
    const float* __restrict__ a_dst, unsigned short* __restrict__ h1b, float* __restrict__ ssrc,
    float* __restrict__ sdst) {
    __shared__ unsigned short As[128 * 40];
    __shared__ unsigned short Bs[64 * 40];
    int tid = threadIdx.x, w = tid >> 6, l = tid & 63, lo = l & 15, hi = l >> 4;
    int m0 = blockIdx.x * 128;
    f32x4 acc[2][4];
#pragma unroll
    for (int i = 0; i < 2; ++i)
#pragma unroll
        for (int j = 0; j < 4; ++j) acc[i][j] = (f32x4){0.f, 0.f, 0.f, 0.f};
    int arow4 = tid >> 2, aseg = tid & 3;
    for (int k0 = 0; k0 < KF; k0 += 32) {
#pragma unroll
        for (int hf = 0; hf < 2; ++hf) {
            int arow = hf * 64 + arow4;
            uint4 va = {0, 0, 0, 0};
            if (m0 + arow < N_NODES)
                va = *(const uint4*)(A + (size_t)(m0 + arow) * KF + k0 + aseg * 8);
            *(uint4*)&As[arow * 40 + aseg * 8] = va;
        }
        uint4 vb = *(const uint4*)(Bt + (size_t)arow4 * KF + k0 + aseg * 8);
        *(uint4*)&Bs[arow4 * 40 + aseg * 8] = vb;
        __syncthreads();
        short8 af[2], bf[4];
#pragma unroll
        for (int fa = 0; fa < 2; ++fa)
            af[fa] = *(const short8*)&As[(w * 32 + fa * 16 + lo) * 40 + hi * 8];
#pragma unroll
        for (int nf = 0; nf < 4; ++nf) bf[nf] = *(const short8*)&Bs[(nf * 16 + lo) * 40 + hi * 8];
#pragma unroll
        for (int fa = 0; fa < 2; ++fa)
#pragma unroll
            for (int nf = 0; nf < 4; ++nf)
                acc[fa][nf] =
                    __builtin_amdgcn_mfma_f32_16x16x32_bf16(af[fa], bf[nf], acc[fa][nf], 0, 0, 0);
        __syncthreads();
    }
    float asv[4], adv[4], bv[4];
#pragma unroll
    for (int nf = 0; nf < 4; ++nf) {
        asv[nf] = a_src[nf * 16 + lo];
        adv[nf] = a_dst[nf * 16 + lo];
        bv[nf] = b01[nf * 16 + lo];
    }
#pragma unroll
    for (int fa = 0; fa < 2; ++fa)
#pragma unroll
        for (int r = 0; r < 4; ++r) {
            int row = m0 + w * 32 + fa * 16 + hi * 4 + r;
#pragma unroll
            for (int nf = 0; nf < 4; ++nf) {
                float v = acc[fa][nf][r] + bv[nf];
                if (row < N_NODES) h1b[(size_t)row * HC1 + nf * 16 + lo] = f2bf(v);
                float ps = v * asv[nf], pd = v * adv[nf];
                for (int m = 1; m < 16; m <<= 1) {
                    ps += __shfl_xor(ps, m);
                    pd += __shfl_xor(pd, m);
                }
                if (lo == 0 && row < N_NODES) {
                    ssrc[row * 4 + nf] = ps;
                    sdst[row * 4 + nf] = pd;
                }
            }
        }
}

// ---------------------------------------------------------------------------
// Layer-1 aggregation: 8-lane groups (8 gather chains/wave), lane owns 8
// channels (one uint4 16B load), head = lo>>1. 2-deep esrc prefetch.
// Packed bf16 weights; final output stored non-temporal (never re-read).
__global__ __launch_bounds__(256) void k_agg1(
    const unsigned short* __restrict__ h1b, const int* __restrict__ esrc,
    const unsigned* __restrict__ ew1p, const int* __restrict__ rowptr,
    const float* __restrict__ bias, float* __restrict__ out) {
    int grp = threadIdx.x >> 3, lo = threadIdx.x & 7;
    int n = blockIdx.x * 32 + grp;
    if (n >= N_NODES) return;
    int head = lo >> 1;
    int wsel = head >> 1, hsel = head & 1;  // word index, half index
    int p0 = rowptr[n], p1 = rowptr[n + 1];
    float a0 = 0, a1 = 0, a2 = 0, a3 = 0, a4 = 0, a5 = 0, a6 = 0, a7 = 0, ss = 0;
    unsigned ew_cur = ew1p[p0 * 2 + wsel];
    uint4 h_cur = *(const uint4*)(h1b + (size_t)esrc[p0] * HC1 + lo * 8);
    int s_nxt = (p0 + 1 < p1) ? esrc[p0 + 1] : 0;
    for (int p = p0; p < p1; ++p) {
        unsigned ew = ew_cur;
        uint4 hv = h_cur;
        if (p + 1 < p1) {
            ew_cur = ew1p[(p + 1) * 2 + wsel];
            h_cur = *(const uint4*)(h1b + (size_t)s_nxt * HC1 + lo * 8);
            if (p + 2 < p1) s_nxt = esrc[p + 2];
        }
        float e = bf2f(hsel ? (ew >> 16) : (ew & 0xffff));
        a0 += e * bf2f(hv.x & 0xffff);
        a1 += e * bf2f(hv.x >> 16);
        a2 += e * bf2f(hv.y & 0xffff);
        a3 += e * bf2f(hv.y >> 16);
        a4 += e * bf2f(hv.z & 0xffff);
        a5 += e * bf2f(hv.z >> 16);
        a6 += e * bf2f(hv.w & 0xffff);
        a7 += e * bf2f(hv.w >> 16);
        ss += e;
    }
    float inv = 1.f / (ss + 1e-16f);
    float4 b0 = *(const float4*)(bias + lo * 8);
    float4 b1 = *(const float4*)(bias + lo * 8 + 4);
    size_t o = (size_t)n * HC1 + lo * 8;
    float4 r0 = make_float4(a0 * inv + b0.x, a1 * inv + b0.y, a2 * inv + b0.z, a3 * inv + b0.w);
    float4 r1 = make_float4(a4 * inv + b1.x, a5 * inv + b1.y, a6 * inv + b1.z, a7 * inv + b1.w);
    float* po = out + o;
    __builtin_nontemporal_store(r0.x, po + 0);
    __builtin_nontemporal_store(r0.y, po + 1);
    __builtin_nontemporal_store(r0.z, po + 2);
    __builtin_nontemporal_store(r0.w, po + 3);
    __builtin_nontemporal_store(r1.x, po + 4);
    __builtin_nontemporal_store(r1.y, po + 5);
    __builtin_nontemporal_store(r1.z, po + 6);
    __builtin_nontemporal_store(r1.w, po + 7);
}

// ---------------------------------------------------------------------------
extern "C" void kernel_launch(void* const* d_in, const int* in_sizes, int n_in, void* d_out,
                              int out_size, void* d_ws, size_t ws_size, hipStream_t stream) {
    const float* x = (const float*)d_in[0];
    const int* ei = (const int*)d_in[1];
    const float* ts = (const float*)d_in[2];
    const float* time_w = (const float*)d_in[3];
    const float* time_b = (const float*)d_in[4];
    const float* W0 = (const float*)d_in[5];
    const float* att_src0 = (const float*)d_in[6];
    const float* att_dst0 = (const float*)d_in[7];
    const float* lin_edge0 = (const float*)d_in[8];
    const float* att_edge0 = (const float*)d_in[9];
    const float* bias0 = (const float*)d_in[10];
    const float* W1 = (const float*)d_in[11];
    const float* att_src1 = (const float*)d_in[12];
    const float* att_dst1 = (const float*)d_in[13];
    const float* lin_edge1 = (const float*)d_in[14];
    const float* att_edge1 = (const float*)d_in[15];
    const float* bias1 = (const float*)d_in[16];
    float* out = (float*)d_out;

    char* ws = (char*)d_ws;
    size_t off = 0;
    auto alloc = [&](size_t bytes) -> void* {
        void* p = ws + off;
        off = (off + bytes + 255) & ~(size_t)255;
        return p;
    };
    unsigned short* xb = (unsigned short*)alloc((size_t)N_NODES * IN_F * 2);
    unsigned short* aggx = (unsigned short*)alloc((size_t)N_NODES * KF * 2);
    unsigned short* h1b = (unsigned short*)alloc((size_t)N_NODES * HC1 * 2);
    unsigned short* W01t = (unsigned short*)alloc((size_t)HC1 * KF * 2);
    float* b01 = (float*)alloc(HC1 * 4);
    float* as0 = (float*)alloc(4 * IN_F * 4);
    float* ad0 = (float*)alloc(4 * IN_F * 4);
    float* tab0 = (float*)alloc((size_t)(TAB + 1) * 4 * 4);
    float* tab1 = (float*)alloc((size_t)(TAB + 1) * 4 * 4);
    unsigned* ew0p = (unsigned*)alloc((size_t)ET * 8);
    unsigned* ew1p = (unsigned*)alloc((size_t)ET * 8);
    float* ssrc0 = (float*)alloc((size_t)N_NODES * 4 * 4);
    float* sdst0 = (float*)alloc((size_t)N_NODES * 4 * 4);
    float* ssrc1 = (float*)alloc((size_t)N_NODES * 4 * 4);
    float* sdst1 = (float*)alloc((size_t)N_NODES * 4 * 4);
    float* l0 = (float*)alloc(16);
    float* l1 = (float*)alloc(16);
    float* tsp = (float*)alloc((size_t)ET * 4);
    int* deg = (int*)alloc((size_t)N_NODES * 4);
    int* rowptr = (int*)alloc((size_t)(N_NODES + 1) * 4);
    int* cursor = (int*)alloc((size_t)(N_NODES + 1) * 4);
    int* blocksum = (int*)alloc(256 * 4);
    int* blockoff = (int*)alloc(256 * 4);
    int* bcnt = (int*)alloc(NBUCKET * 4);
    int2* staging = (int2*)alloc((size_t)NBUCKET * BCAP * 8);
    int* esrc = (int*)alloc((size_t)ET * 4);
    int* edst = (int*)alloc((size_t)ET * 4);
    (void)ws_size;
    (void)in_sizes;
    (void)n_in;
    (void)out_size;

    int nb = (N_NODES + 255) / 256;            // 196
    int ebks = (ET + 255) / 256;               // 3321
    int cbks = (N_EDGES + CHUNK - 1) / CHUNK;  // 196
    int gx = (N_NODES + 127) / 128;            // 391
    int nblk16 = (N_NODES + 15) / 16;          // 3125
    int nblk32 = (N_NODES + 31) / 32;          // 1563
    int nblk4 = (N_NODES + 3) / 4;             // 12500

    // Parameter-only precompute (single launch, incl. time-encode tables)
    k_param<<<275, 256, 0, stream>>>(lin_edge0, att_edge0, lin_edge1, att_edge1, W0, att_src0,
                                     att_dst0, W1, bias0, time_w, time_b, l0, l1, as0, ad0, W01t,
                                     b01, tab0, tab1);

    // Node features + layer-0 scores + deg/bcnt zeroing
    k_xbs<<<nblk4, 256, 0, stream>>>(x, as0, ad0, xb, ssrc0, sdst0, deg, bcnt);

    // Bucket edges into fixed windows + per-node degree count (fused)
    k_bucketA<<<cbks, 1024, 0, stream>>>(ei, ts, deg, bcnt, staging);

    // CSR (self-loop slot reserved at the end of each row)
    k_scan_block<<<nb, 256, 0, stream>>>(deg, rowptr, blocksum, N_NODES);
    k_scan_top<<<1, 256, 0, stream>>>(blocksum, blockoff, nb);
    k_finalize<<<nb, 256, 0, stream>>>(rowptr, blockoff, deg, cursor, edst, esrc, tsp, ssrc0,
                                       sdst0, l0, ew0p);
    k_bucketB<<<NBUCKET, 256, 0, stream>>>(bcnt, staging, cursor, esrc, tsp, ssrc0, sdst0, tab0,
                                           ew0p);

    // Layer 0: aggregate x
    k_aggx<<<nblk16, 256, 0, stream>>>(xb, esrc, ew0p, rowptr, aggx);

    // Layer 1: fused GEMM (W0*W1) + scores, edge weights, aggregate
    k_gemm1s<<<gx, 256, 0, stream>>>(aggx, W01t, b01, att_src1, att_dst1, h1b, ssrc1, sdst1);
    k_ew1<<<ebks, 256, 0, stream>>>(esrc, edst, tsp, tab1, l1, ssrc1, sdst1, ew1p);
    k_agg1<<<nblk32, 256, 0, stream>>>(h1b, esrc, ew1p, rowptr, bias1, out);
}

// Round 20
// 218.583 us; speedup vs baseline: 1.1335x; 1.0041x over previous
//
#include <hip/hip_runtime.h>
#include <math.h>

#define N_NODES 50000
#define N_EDGES 800000
#define ET (N_EDGES + N_NODES)
#define IN_F 128
#define TDIM 64
#define HEADS 4
#define C0 64
#define C1 16
#define HC0 256
#define HC1 64
#define KF 512 /* fused K = 4*IN_F */
#define SLOPE 0.2f
#define TAB 4096
#define BSHIFT 7
#define NBUCKET 391 /* ceil(50000/128) */
#define BCAP 4096   /* staging capacity per bucket (E~2048, sigma~45) */
#define CHUNK 4096  /* edges per block; 196 blocks x 1024 threads */

using short8 = __attribute__((ext_vector_type(8))) short;
using f32x4 = __attribute__((ext_vector_type(4))) float;

__device__ __forceinline__ float bf2f(unsigned u16) { return __uint_as_float(u16 << 16); }
__device__ __forceinline__ unsigned short f2bf(float f) {
    unsigned u = __float_as_uint(f);
    return (unsigned short)((u + 0x7fffu + ((u >> 16) & 1u)) >> 16);
}
__device__ __forceinline__ unsigned pk2(float lo, float hi) {
    return (unsigned)f2bf(lo) | ((unsigned)f2bf(hi) << 16);
}
__device__ __forceinline__ float lrelu(float a) { return a >= 0.f ? a : SLOPE * a; }

// ---------------------------------------------------------------------------
// ALL parameter-only precompute in ONE launch (275 blocks x 256).
__global__ __launch_bounds__(256) void k_param(
    const float* __restrict__ le0, const float* __restrict__ at0, const float* __restrict__ le1,
    const float* __restrict__ at1, const float* __restrict__ W0, const float* __restrict__ asr,
    const float* __restrict__ ads, const float* __restrict__ W1, const float* __restrict__ bias0,
    const float* __restrict__ tw, const float* __restrict__ tb, float* __restrict__ l0,
    float* __restrict__ l1, float* __restrict__ as0, float* __restrict__ ad0,
    unsigned short* __restrict__ W01t, float* __restrict__ b01, float* __restrict__ tab0,
    float* __restrict__ tab1) {
    int b = blockIdx.x, tid = threadIdx.x;
    int h = tid >> 6, c = tid & 63;
    if (b == 0) {
        float s0 = 0.f;
        for (int td = 0; td < TDIM; ++td) s0 += le0[td * HC0 + h * C0 + c];
        s0 *= at0[h * C0 + c];
        for (int m = 1; m < 64; m <<= 1) s0 += __shfl_xor(s0, m);
        if (c == 0) l0[h] = s0;
        float s1 = 0.f;
        if (c < C1) {
            for (int td = 0; td < TDIM; ++td) s1 += le1[td * HC1 + h * C1 + c];
            s1 *= at1[h * C1 + c];
        }
        for (int m = 1; m < 16; m <<= 1) s1 += __shfl_xor(s1, m);
        if (c == 0) l1[h] = s1;
    } else if (b < 129) {
        int k = b - 1;
        float wv = W0[k * HC0 + h * C0 + c];
        float ps = wv * asr[h * C0 + c];
        float pd = wv * ads[h * C0 + c];
        for (int m = 1; m < 64; m <<= 1) {
            ps += __shfl_xor(ps, m);
            pd += __shfl_xor(pd, m);
        }
        if (c == 0) {
            as0[h * IN_F + k] = ps;
            ad0[h * IN_F + k] = pd;
        }
    } else if (b < 257) {
        int hk = (b - 129) * 4 + (tid >> 6);
        int c1 = tid & 63;
        int hh = hk >> 7, k = hk & 127;
        float acc = 0.f;
        for (int c0 = 0; c0 < C0; ++c0)
            acc += W0[k * HC0 + hh * C0 + c0] * W1[(size_t)(hh * C0 + c0) * HC1 + c1];
        W01t[(size_t)c1 * KF + hk] = f2bf(acc);
    } else if (b == 257) {
        if (tid < 64) {
            float acc = 0.f;
            for (int k = 0; k < HC0; ++k) acc += bias0[k] * W1[(size_t)k * HC1 + tid];
            b01[tid] = acc;
        }
    } else {
        // time-encode table blocks: self-compute v contraction in LDS
        __shared__ float sv0[TDIM * 4], sv1[TDIM * 4], sw[TDIM], sb[TDIM];
        int td = tid >> 2, hh = tid & 3;
        float v0l = 0.f;
        for (int c0 = 0; c0 < C0; ++c0) v0l += le0[td * HC0 + hh * C0 + c0] * at0[hh * C0 + c0];
        sv0[td * 4 + hh] = v0l;
        float v1l = 0.f;
        for (int c0 = 0; c0 < C1; ++c0) v1l += le1[td * HC1 + hh * C1 + c0] * at1[hh * C1 + c0];
        sv1[td * 4 + hh] = v1l;
        if (tid < TDIM) {
            sw[tid] = tw[tid];
            sb[tid] = tb[tid];
        }
        __syncthreads();
        int i = (b - 258) * 256 + tid;
        if (i > TAB) return;
        float time = (float)i / (float)TAB;
        float a00 = 0, a01 = 0, a02 = 0, a03 = 0, a10 = 0, a11 = 0, a12 = 0, a13 = 0;
#pragma unroll 8
        for (int d = 0; d < TDIM; ++d) {
            float f = fabsf(__cosf(time * sw[d] + sb[d]));
            a00 += f * sv0[d * 4 + 0];
            a01 += f * sv0[d * 4 + 1];
            a02 += f * sv0[d * 4 + 2];
            a03 += f * sv0[d * 4 + 3];
            a10 += f * sv1[d * 4 + 0];
            a11 += f * sv1[d * 4 + 1];
            a12 += f * sv1[d * 4 + 2];
            a13 += f * sv1[d * 4 + 3];
        }
        ((float4*)tab0)[i] = make_float4(a00, a01, a02, a03);
        ((float4*)tab1)[i] = make_float4(a10, a11, a12, a13);
    }
}

// ---------------------------------------------------------------------------
// Fused x->bf16 + layer-0 scores + deg/bcnt zeroing. One wave per node.
__global__ __launch_bounds__(256) void k_xbs(const float* __restrict__ x,
                                             const float* __restrict__ as0,
                                             const float* __restrict__ ad0,
                                             unsigned short* __restrict__ xb,
                                             float* __restrict__ ssrc, float* __restrict__ sdst,
                                             int* __restrict__ deg, int* __restrict__ bcnt) {
    if (blockIdx.x < 196) {
        int i = blockIdx.x * 256 + threadIdx.x;
        if (i < N_NODES) deg[i] = 0;
    }
    if (blockIdx.x >= 196 && blockIdx.x < 198) {
        int i = (blockIdx.x - 196) * 256 + threadIdx.x;
        if (i < NBUCKET) bcnt[i] = 0;
    }
    int w = threadIdx.x >> 6, l = threadIdx.x & 63;
    int n = blockIdx.x * 4 + w;
    if (n >= N_NODES) return;
    float2 xv = *(const float2*)(x + (size_t)n * IN_F + l * 2);
    *(unsigned*)(xb + (size_t)n * IN_F + l * 2) = pk2(xv.x, xv.y);
    float ps[4], pd[4];
#pragma unroll
    for (int h = 0; h < 4; ++h) {
        float2 a = *(const float2*)(as0 + h * IN_F + l * 2);
        float2 d = *(const float2*)(ad0 + h * IN_F + l * 2);
        ps[h] = xv.x * a.x + xv.y * a.y;
        pd[h] = xv.x * d.x + xv.y * d.y;
    }
#pragma unroll
    for (int m = 1; m < 64; m <<= 1) {
#pragma unroll
        for (int h = 0; h < 4; ++h) {
            ps[h] += __shfl_xor(ps[h], m);
            pd[h] += __shfl_xor(pd[h], m);
        }
    }
    if (l == 0) {
#pragma unroll
        for (int h = 0; h < 4; ++h) {
            ssrc[n * 4 + h] = ps[h];
            sdst[n * 4 + h] = pd[h];
        }
    }
}

// ---------------------------------------------------------------------------
// Phase A: bucket edges by dst>>7 into FIXED per-bucket staging windows
// (b*BCAP) AND count per-node degrees. 196 blocks x 1024 threads (16 waves).
// Staging packed int2: .x = (src<<7) | (dst & 127), .y = ts bits
__global__ __launch_bounds__(1024) void k_bucketA(const int* __restrict__ ei,
                                                  const float* __restrict__ ts,
                                                  int* __restrict__ deg, int* __restrict__ bcnt,
                                                  int2* __restrict__ staging) {
    __shared__ int cnt[NBUCKET], base[NBUCKET];
    int tid = threadIdx.x;
    int e0 = blockIdx.x * CHUNK;
    for (int i = tid; i < NBUCKET; i += 1024) cnt[i] = 0;
    __syncthreads();
    int key[4], b[4], tv[4];
#pragma unroll
    for (int i = 0; i < 4; ++i) {
        int tt = e0 + i * 1024 + tid;
        if (tt < N_EDGES) {
            int s = ei[tt];
            int d = ei[N_EDGES + tt];
            key[i] = (s << BSHIFT) | (d & ((1 << BSHIFT) - 1));
            b[i] = d >> BSHIFT;
            tv[i] = __float_as_int(ts[tt]);
            atomicAdd(&cnt[b[i]], 1);
            atomicAdd(&deg[d], 1);  // fused per-node degree count
        } else {
            b[i] = -1;
        }
    }
    __syncthreads();
    for (int i = tid; i < NBUCKET; i += 1024) {
        int c = cnt[i];
        base[i] = c ? atomicAdd(&bcnt[i], c) : 0;
        cnt[i] = 0;  // reuse as running cursor
    }
    __syncthreads();
#pragma unroll
    for (int i = 0; i < 4; ++i) {
        if (b[i] >= 0) {
            int off = atomicAdd(&cnt[b[i]], 1);
            staging[(size_t)b[i] * BCAP + base[b[i]] + off] = make_int2(key[i], tv[i]);
        }
    }
}

// ---------------------------------------------------------------------------
// Per-block inclusive scan of (deg+1); blocksum for cross-block offsets.
__global__ void k_scan_block(const int* __restrict__ deg, int* __restrict__ rowptr,
                             int* __restrict__ blocksum, int n) {
    __shared__ int buf[256];
    int tid = threadIdx.x, i = blockIdx.x * 256 + tid;
    int v = (i < n) ? (deg[i] + 1) : 0;
    buf[tid] = v;
    __syncthreads();
    for (int off = 1; off < 256; off <<= 1) {
        int t = (tid >= off) ? buf[tid - off] : 0;
        __syncthreads();
        buf[tid] += t;
        __syncthreads();
    }
    if (i < n) rowptr[i + 1] = buf[tid];
    if (tid == 255) blocksum[blockIdx.x] = buf[255];
}

// Finalize (scan_top folded in): each block wave-reduces its exclusive block
// offset from blocksum[0..b); then rowptr += off, cursor, edst spans,
// self-loop esrc/tsp/ew0p (packed bf16x4).
__global__ __launch_bounds__(256) void k_finalize(
    int* __restrict__ rowptr, const int* __restrict__ blocksum, const int* __restrict__ deg,
    int* __restrict__ cursor, int* __restrict__ edst, int* __restrict__ esrc,
    float* __restrict__ tsp, const float* __restrict__ ssrc0, const float* __restrict__ sdst0,
    const float* __restrict__ l0, unsigned* __restrict__ ew0p) {
    __shared__ int s_off;
    if (threadIdx.x < 64) {
        int acc = 0;
        for (int i = threadIdx.x; i < blockIdx.x; i += 64) acc += blocksum[i];
        for (int m = 1; m < 64; m <<= 1) acc += __shfl_xor(acc, m);
        if (threadIdx.x == 0) s_off = acc;
    }
    __syncthreads();
    int boff = s_off;
    int i = blockIdx.x * 256 + threadIdx.x;
    if (i >= N_NODES) return;
    int v = rowptr[i + 1] + boff;
    rowptr[i + 1] = v;
    int start = v - deg[i] - 1;
    cursor[i] = start;
    if (i == 0) rowptr[0] = 0;
    for (int p = start; p < v; ++p) edst[p] = i;  // includes self-loop slot
    esrc[v - 1] = i;                              // self-loop src
    tsp[v - 1] = -1.f;                            // self-loop sentinel
    float4 lv = ((const float4*)l0)[0];
    float4 sv = ((const float4*)ssrc0)[i];
    float4 dv = ((const float4*)sdst0)[i];
    float w0 = __expf(lrelu(sv.x + dv.x + lv.x));
    float w1 = __expf(lrelu(sv.y + dv.y + lv.y));
    float w2 = __expf(lrelu(sv.z + dv.z + lv.z));
    float w3 = __expf(lrelu(sv.w + dv.w + lv.w));
    ((uint2*)ew0p)[v - 1] = make_uint2(pk2(w0, w1), pk2(w2, w3));
}

// ---------------------------------------------------------------------------
// Phase B: one block per bucket; scatter from fixed staging window into final
// CSR slots (L2-hot) AND compute layer-0 edge softmax weights (packed bf16x4).
__global__ __launch_bounds__(256) void k_bucketB(
    const int* __restrict__ bcnt, const int2* __restrict__ staging, int* __restrict__ cursor,
    int* __restrict__ esrc, float* __restrict__ tsp, const float* __restrict__ ssrc0,
    const float* __restrict__ sdst0, const float* __restrict__ tab0,
    unsigned* __restrict__ ew0p) {
    int b = blockIdx.x;
    int hi = bcnt[b];
    const int2* win = staging + (size_t)b * BCAP;
    for (int p = threadIdx.x; p < hi; p += 256) {
        int2 kt = win[p];
        int s = ((unsigned)kt.x) >> BSHIFT;
        int d = (b << BSHIFT) | (kt.x & ((1 << BSHIFT) - 1));
        int q = atomicAdd(&cursor[d], 1);
        esrc[q] = s;
        float tv = __int_as_float(kt.y);
        tsp[q] = tv;
        float f = tv * (float)TAB;
        int i = (int)f;
        i = i > TAB - 1 ? TAB - 1 : i;
        float fr = f - (float)i;
        float4 t0 = ((const float4*)tab0)[i];
        float4 t1 = ((const float4*)tab0)[i + 1];
        float4 sv = ((const float4*)ssrc0)[s];
        float4 dv = ((const float4*)sdst0)[d];
        float w0 = __expf(lrelu(sv.x + dv.x + t0.x + fr * (t1.x - t0.x)));
        float w1 = __expf(lrelu(sv.y + dv.y + t0.y + fr * (t1.y - t0.y)));
        float w2 = __expf(lrelu(sv.z + dv.z + t0.z + fr * (t1.z - t0.z)));
        float w3 = __expf(lrelu(sv.w + dv.w + t0.w + fr * (t1.w - t0.w)));
        ((uint2*)ew0p)[q] = make_uint2(pk2(w0, w1), pk2(w2, w3));
    }
}

// ---------------------------------------------------------------------------
// Layer-1 edge weights (edge-parallel, streaming, table lerp, packed bf16x4).
__global__ void k_ew1(const int* __restrict__ esrc, const int* __restrict__ edst,
                      const float* __restrict__ tsp, const float* __restrict__ tab1,
                      const float* __restrict__ l1, const float* __restrict__ ssrc,
                      const float* __restrict__ sdst, unsigned* __restrict__ ew1p) {
    int p = blockIdx.x * blockDim.x + threadIdx.x;
    if (p >= ET) return;
    float tv = tsp[p];
    float4 av;
    if (tv < 0.f) {
        av = ((const float4*)l1)[0];
    } else {
        float f = tv * (float)TAB;
        int i = (int)f;
        i = i > TAB - 1 ? TAB - 1 : i;
        float fr = f - (float)i;
        float4 t0 = ((const float4*)tab1)[i];
        float4 t1 = ((const float4*)tab1)[i + 1];
        av.x = t0.x + fr * (t1.x - t0.x);
        av.y = t0.y + fr * (t1.y - t0.y);
        av.z = t0.z + fr * (t1.z - t0.z);
        av.w = t0.w + fr * (t1.w - t0.w);
    }
    int s = esrc[p], d = edst[p];
    float4 sv = ((const float4*)ssrc)[s];
    float4 dv = ((const float4*)sdst)[d];
    float w0 = __expf(lrelu(sv.x + dv.x + av.x));
    float w1 = __expf(lrelu(sv.y + dv.y + av.y));
    float w2 = __expf(lrelu(sv.z + dv.z + av.z));
    float w3 = __expf(lrelu(sv.w + dv.w + av.w));
    ((uint2*)ew1p)[p] = make_uint2(pk2(w0, w1), pk2(w2, w3));
}

// ---------------------------------------------------------------------------
// Layer-0 aggregation of x, precomputed packed weights, pipelined gather.
// 4 nodes per wave (16-lane groups), lane owns 8 channels (all 4 heads).
__global__ __launch_bounds__(256) void k_aggx(const unsigned short* __restrict__ xb,
                                              const int* __restrict__ esrc,
                                              const unsigned* __restrict__ ew0p,
                                              const int* __restrict__ rowptr,
                                              unsigned short* __restrict__ aggx) {
    int grp = threadIdx.x >> 4, lo = threadIdx.x & 15;
    int n = blockIdx.x * 16 + grp;
    if (n >= N_NODES) return;
    int p0 = rowptr[n], p1 = rowptr[n + 1];  // p1 > p0 always (self-loop)
    float acc[4][8];
#pragma unroll
    for (int h = 0; h < 4; ++h)
#pragma unroll
        for (int j = 0; j < 8; ++j) acc[h][j] = 0.f;
    float ss0 = 0, ss1 = 0, ss2 = 0, ss3 = 0;
    uint2 e_cur = ((const uint2*)ew0p)[p0];
    uint4 x_cur = *(const uint4*)(xb + (size_t)esrc[p0] * IN_F + lo * 8);
    int s_nxt = (p0 + 1 < p1) ? esrc[p0 + 1] : 0;
    for (int p = p0; p < p1; ++p) {
        uint2 ev = e_cur;
        uint4 xv = x_cur;
        if (p + 1 < p1) {
            e_cur = ((const uint2*)ew0p)[p + 1];
            x_cur = *(const uint4*)(xb + (size_t)s_nxt * IN_F + lo * 8);
            if (p + 2 < p1) s_nxt = esrc[p + 2];
        }
        float e0 = bf2f(ev.x & 0xffff), e1 = bf2f(ev.x >> 16);
        float e2 = bf2f(ev.y & 0xffff), e3 = bf2f(ev.y >> 16);
        float f[8];
        f[0] = bf2f(xv.x & 0xffff);
        f[1] = bf2f(xv.x >> 16);
        f[2] = bf2f(xv.y & 0xffff);
        f[3] = bf2f(xv.y >> 16);
        f[4] = bf2f(xv.z & 0xffff);
        f[5] = bf2f(xv.z >> 16);
        f[6] = bf2f(xv.w & 0xffff);
        f[7] = bf2f(xv.w >> 16);
#pragma unroll
        for (int j = 0; j < 8; ++j) {
            acc[0][j] += e0 * f[j];
            acc[1][j] += e1 * f[j];
            acc[2][j] += e2 * f[j];
            acc[3][j] += e3 * f[j];
        }
        ss0 += e0;
        ss1 += e1;
        ss2 += e2;
        ss3 += e3;
    }
    float inv[4] = {1.f / (ss0 + 1e-16f), 1.f / (ss1 + 1e-16f), 1.f / (ss2 + 1e-16f),
                    1.f / (ss3 + 1e-16f)};
    size_t base = (size_t)n * KF + lo * 8;
#pragma unroll
    for (int h = 0; h < 4; ++h) {
        uint4 r;
        r.x = pk2(acc[h][0] * inv[h], acc[h][1] * inv[h]);
        r.y = pk2(acc[h][2] * inv[h], acc[h][3] * inv[h]);
        r.z = pk2(acc[h][4] * inv[h], acc[h][5] * inv[h]);
        r.w = pk2(acc[h][6] * inv[h], acc[h][7] * inv[h]);
        *(uint4*)(aggx + base + h * IN_F) = r;
    }
}

// ---------------------------------------------------------------------------
// h1 = aggx @ W01t^T + b01 ; writes h1b (bf16) + fused layer-1 scores
// (epilogue lives here: compute-bound kernel, registers are cheap).
__global__ __launch_bounds__(256) void k_gemm1s(
    const unsigned short* __restrict__ A, const unsigned short* __restrict__ Bt,
    const float* __restrict__ b01, const float* __restrict__ a_src,
    const float* __restrict__ a_dst, unsigned short* __restrict__ h1b, float* __restrict__ ssrc,
    float* __restrict__ sdst) {
    __shared__ unsigned short As[128 * 40];
    __shared__ unsigned short Bs[64 * 40];
    int tid = threadIdx.x, w = tid >> 6, l = tid & 63, lo = l & 15, hi = l >> 4;
    int m0 = blockIdx.x * 128;
    f32x4 acc[2][4];
#pragma unroll
    for (int i = 0; i < 2; ++i)
#pragma unroll
        for (int j = 0; j < 4; ++j) acc[i][j] = (f32x4){0.f, 0.f, 0.f, 0.f};
    int arow4 = tid >> 2, aseg = tid & 3;
    for (int k0 = 0; k0 < KF; k0 += 32) {
#pragma unroll
        for (int hf = 0; hf < 2; ++hf) {
            int arow = hf * 64 + arow4;
            uint4 va = {0, 0, 0, 0};
            if (m0 + arow < N_NODES)
                va = *(const uint4*)(A + (size_t)(m0 + arow) * KF + k0 + aseg * 8);
            *(uint4*)&As[arow * 40 + aseg * 8] = va;
        }
        uint4 vb = *(const uint4*)(Bt + (size_t)arow4 * KF + k0 + aseg * 8);
        *(uint4*)&Bs[arow4 * 40 + aseg * 8] = vb;
        __syncthreads();
        short8 af[2], bf[4];
#pragma unroll
        for (int fa = 0; fa < 2; ++fa)
            af[fa] = *(const short8*)&As[(w * 32 + fa * 16 + lo) * 40 + hi * 8];
#pragma unroll
        for (int nf = 0; nf < 4; ++nf) bf[nf] = *(const short8*)&Bs[(nf * 16 + lo) * 40 + hi * 8];
#pragma unroll
        for (int fa = 0; fa < 2; ++fa)
#pragma unroll
            for (int nf = 0; nf < 4; ++nf)
                acc[fa][nf] =
                    __builtin_amdgcn_mfma_f32_16x16x32_bf16(af[fa], bf[nf], acc[fa][nf], 0, 0, 0);
        __syncthreads();
    }
    float asv[4], adv[4], bv[4];
#pragma unroll
    for (int nf = 0; nf < 4; ++nf) {
        asv[nf] = a_src[nf * 16 + lo];
        adv[nf] = a_dst[nf * 16 + lo];
        bv[nf] = b01[nf * 16 + lo];
    }
#pragma unroll
    for (int fa = 0; fa < 2; ++fa)
#pragma unroll
        for (int r = 0; r < 4; ++r) {
            int row = m0 + w * 32 + fa * 16 + hi * 4 + r;
#pragma unroll
            for (int nf = 0; nf < 4; ++nf) {
                float v = acc[fa][nf][r] + bv[nf];
                if (row < N_NODES) h1b[(size_t)row * HC1 + nf * 16 + lo] = f2bf(v);
                float ps = v * asv[nf], pd = v * adv[nf];
                for (int m = 1; m < 16; m <<= 1) {
                    ps += __shfl_xor(ps, m);
                    pd += __shfl_xor(pd, m);
                }
                if (lo == 0 && row < N_NODES) {
                    ssrc[row * 4 + nf] = ps;
                    sdst[row * 4 + nf] = pd;
                }
            }
        }
}

// ---------------------------------------------------------------------------
// Layer-1 aggregation: 8-lane groups (8 gather chains/wave), lane owns 8
// channels (one uint4 16B load), head = lo>>1. 2-deep esrc prefetch.
// Packed bf16 weights; final output stored non-temporal (never re-read).
__global__ __launch_bounds__(256) void k_agg1(
    const unsigned short* __restrict__ h1b, const int* __restrict__ esrc,
    const unsigned* __restrict__ ew1p, const int* __restrict__ rowptr,
    const float* __restrict__ bias, float* __restrict__ out) {
    int grp = threadIdx.x >> 3, lo = threadIdx.x & 7;
    int n = blockIdx.x * 32 + grp;
    if (n >= N_NODES) return;
    int head = lo >> 1;
    int wsel = head >> 1, hsel = head & 1;  // word index, half index
    int p0 = rowptr[n], p1 = rowptr[n + 1];
    float a0 = 0, a1 = 0, a2 = 0, a3 = 0, a4 = 0, a5 = 0, a6 = 0, a7 = 0, ss = 0;
    unsigned ew_cur = ew1p[p0 * 2 + wsel];
    uint4 h_cur = *(const uint4*)(h1b + (size_t)esrc[p0] * HC1 + lo * 8);
    int s_nxt = (p0 + 1 < p1) ? esrc[p0 + 1] : 0;
    for (int p = p0; p < p1; ++p) {
        unsigned ew = ew_cur;
        uint4 hv = h_cur;
        if (p + 1 < p1) {
            ew_cur = ew1p[(p + 1) * 2 + wsel];
            h_cur = *(const uint4*)(h1b + (size_t)s_nxt * HC1 + lo * 8);
            if (p + 2 < p1) s_nxt = esrc[p + 2];
        }
        float e = bf2f(hsel ? (ew >> 16) : (ew & 0xffff));
        a0 += e * bf2f(hv.x & 0xffff);
        a1 += e * bf2f(hv.x >> 16);
        a2 += e * bf2f(hv.y & 0xffff);
        a3 += e * bf2f(hv.y >> 16);
        a4 += e * bf2f(hv.z & 0xffff);
        a5 += e * bf2f(hv.z >> 16);
        a6 += e * bf2f(hv.w & 0xffff);
        a7 += e * bf2f(hv.w >> 16);
        ss += e;
    }
    float inv = 1.f / (ss + 1e-16f);
    float4 b0 = *(const float4*)(bias + lo * 8);
    float4 b1 = *(const float4*)(bias + lo * 8 + 4);
    size_t o = (size_t)n * HC1 + lo * 8;
    float4 r0 = make_float4(a0 * inv + b0.x, a1 * inv + b0.y, a2 * inv + b0.z, a3 * inv + b0.w);
    float4 r1 = make_float4(a4 * inv + b1.x, a5 * inv + b1.y, a6 * inv + b1.z, a7 * inv + b1.w);
    float* po = out + o;
    __builtin_nontemporal_store(r0.x, po + 0);
    __builtin_nontemporal_store(r0.y, po + 1);
    __builtin_nontemporal_store(r0.z, po + 2);
    __builtin_nontemporal_store(r0.w, po + 3);
    __builtin_nontemporal_store(r1.x, po + 4);
    __builtin_nontemporal_store(r1.y, po + 5);
    __builtin_nontemporal_store(r1.z, po + 6);
    __builtin_nontemporal_store(r1.w, po + 7);
}

// ---------------------------------------------------------------------------
extern "C" void kernel_launch(void* const* d_in, const int* in_sizes, int n_in, void* d_out,
                              int out_size, void* d_ws, size_t ws_size, hipStream_t stream) {
    const float* x = (const float*)d_in[0];
    const int* ei = (const int*)d_in[1];
    const float* ts = (const float*)d_in[2];
    const float* time_w = (const float*)d_in[3];
    const float* time_b = (const float*)d_in[4];
    const float* W0 = (const float*)d_in[5];
    const float* att_src0 = (const float*)d_in[6];
    const float* att_dst0 = (const float*)d_in[7];
    const float* lin_edge0 = (const float*)d_in[8];
    const float* att_edge0 = (const float*)d_in[9];
    const float* bias0 = (const float*)d_in[10];
    const float* W1 = (const float*)d_in[11];
    const float* att_src1 = (const float*)d_in[12];
    const float* att_dst1 = (const float*)d_in[13];
    const float* lin_edge1 = (const float*)d_in[14];
    const float* att_edge1 = (const float*)d_in[15];
    const float* bias1 = (const float*)d_in[16];
    float* out = (float*)d_out;

    char* ws = (char*)d_ws;
    size_t off = 0;
    auto alloc = [&](size_t bytes) -> void* {
        void* p = ws + off;
        off = (off + bytes + 255) & ~(size_t)255;
        return p;
    };
    unsigned short* xb = (unsigned short*)alloc((size_t)N_NODES * IN_F * 2);
    unsigned short* aggx = (unsigned short*)alloc((size_t)N_NODES * KF * 2);
    unsigned short* h1b = (unsigned short*)alloc((size_t)N_NODES * HC1 * 2);
    unsigned short* W01t = (unsigned short*)alloc((size_t)HC1 * KF * 2);
    float* b01 = (float*)alloc(HC1 * 4);
    float* as0 = (float*)alloc(4 * IN_F * 4);
    float* ad0 = (float*)alloc(4 * IN_F * 4);
    float* tab0 = (float*)alloc((size_t)(TAB + 1) * 4 * 4);
    float* tab1 = (float*)alloc((size_t)(TAB + 1) * 4 * 4);
    unsigned* ew0p = (unsigned*)alloc((size_t)ET * 8);
    unsigned* ew1p = (unsigned*)alloc((size_t)ET * 8);
    float* ssrc0 = (float*)alloc((size_t)N_NODES * 4 * 4);
    float* sdst0 = (float*)alloc((size_t)N_NODES * 4 * 4);
    float* ssrc1 = (float*)alloc((size_t)N_NODES * 4 * 4);
    float* sdst1 = (float*)alloc((size_t)N_NODES * 4 * 4);
    float* l0 = (float*)alloc(16);
    float* l1 = (float*)alloc(16);
    float* tsp = (float*)alloc((size_t)ET * 4);
    int* deg = (int*)alloc((size_t)N_NODES * 4);
    int* rowptr = (int*)alloc((size_t)(N_NODES + 1) * 4);
    int* cursor = (int*)alloc((size_t)(N_NODES + 1) * 4);
    int* blocksum = (int*)alloc(256 * 4);
    int* bcnt = (int*)alloc(NBUCKET * 4);
    int2* staging = (int2*)alloc((size_t)NBUCKET * BCAP * 8);
    int* esrc = (int*)alloc((size_t)ET * 4);
    int* edst = (int*)alloc((size_t)ET * 4);
    (void)ws_size;
    (void)in_sizes;
    (void)n_in;
    (void)out_size;

    int nb = (N_NODES + 255) / 256;            // 196
    int ebks = (ET + 255) / 256;               // 3321
    int cbks = (N_EDGES + CHUNK - 1) / CHUNK;  // 196
    int gx = (N_NODES + 127) / 128;            // 391
    int nblk16 = (N_NODES + 15) / 16;          // 3125
    int nblk32 = (N_NODES + 31) / 32;          // 1563
    int nblk4 = (N_NODES + 3) / 4;             // 12500

    // Parameter-only precompute (single launch, incl. time-encode tables)
    k_param<<<275, 256, 0, stream>>>(lin_edge0, att_edge0, lin_edge1, att_edge1, W0, att_src0,
                                     att_dst0, W1, bias0, time_w, time_b, l0, l1, as0, ad0, W01t,
                                     b01, tab0, tab1);

    // Node features + layer-0 scores + deg/bcnt zeroing
    k_xbs<<<nblk4, 256, 0, stream>>>(x, as0, ad0, xb, ssrc0, sdst0, deg, bcnt);

    // Bucket edges into fixed windows + per-node degree count (fused)
    k_bucketA<<<cbks, 1024, 0, stream>>>(ei, ts, deg, bcnt, staging);

    // CSR (self-loop slot reserved at the end of each row)
    k_scan_block<<<nb, 256, 0, stream>>>(deg, rowptr, blocksum, N_NODES);
    k_finalize<<<nb, 256, 0, stream>>>(rowptr, blocksum, deg, cursor, edst, esrc, tsp, ssrc0,
                                       sdst0, l0, ew0p);
    k_bucketB<<<NBUCKET, 256, 0, stream>>>(bcnt, staging, cursor, esrc, tsp, ssrc0, sdst0, tab0,
                                           ew0p);

    // Layer 0: aggregate x
    k_aggx<<<nblk16, 256, 0, stream>>>(xb, esrc, ew0p, rowptr, aggx);

    // Layer 1: fused GEMM (W0*W1) + scores, edge weights, aggregate
    k_gemm1s<<<gx, 256, 0, stream>>>(aggx, W01t, b01, att_src1, att_dst1, h1b, ssrc1, sdst1);
    k_ew1<<<ebks, 256, 0, stream>>>(esrc, edst, tsp, tab1, l1, ssrc1, sdst1, ew1p);
    k_agg1<<<nblk32, 256, 0, stream>>>(h1b, esrc, ew1p, rowptr, bias1, out);
}